// Round 8
// baseline (279.764 us; speedup 1.0000x reference)
//
#include <hip/hip_runtime.h>
#include <hip/hip_bf16.h>

typedef __attribute__((ext_vector_type(8))) short short8;
typedef __attribute__((ext_vector_type(4))) float f32x4;
typedef __attribute__((ext_vector_type(4))) unsigned int u32x4;
using u16 = unsigned short;
typedef unsigned int u32;

__device__ __forceinline__ u16 f2bf(float f) {
    u32 u = __builtin_bit_cast(u32, f);
    u32 r = u + 0x7FFFu + ((u >> 16) & 1u);
    return (u16)(r >> 16);
}

__device__ __forceinline__ float exp2fast(float x) {
    return __builtin_amdgcn_exp2f(x);  // v_exp_f32
}

__device__ __forceinline__ u32 cvtpk(float lo, float hi) {
    u32 r;
    asm("v_cvt_pk_bf16_f32 %0, %1, %2" : "=v"(r) : "v"(lo), "v"(hi));
    return r;
}

__device__ __forceinline__ void async_load16(const void* g, void* l) {
    __builtin_amdgcn_global_load_lds(
        (const __attribute__((address_space(1))) void*)g,
        (__attribute__((address_space(3))) void*)l, 16, 0, 0);
}

__device__ __forceinline__ void wg_barrier() {
    asm volatile("" ::: "memory");
    __builtin_amdgcn_s_barrier();
    asm volatile("" ::: "memory");
}

// ---------------- weight transpose + f32->bf16 convert: w[K][N] -> wt[N][K] ----------------
__global__ __launch_bounds__(256) void convt_kernel(const float* __restrict__ w,
                                                    u16* __restrict__ wt, int K, int N) {
    __shared__ float tile[32][33];
    int bn = blockIdx.x * 32, bk = blockIdx.y * 32;
    int tx = threadIdx.x & 31, ty = threadIdx.x >> 5;
#pragma unroll
    for (int i = 0; i < 4; i++)
        tile[ty + i * 8][tx] = w[(size_t)(bk + ty + i * 8) * N + bn + tx];
    __syncthreads();
#pragma unroll
    for (int i = 0; i < 4; i++)
        wt[(size_t)(bn + ty + i * 8) * K + bk + tx] = f2bf(tile[tx][ty + i * 8]);
}

// 4 square 1024x1024 transposes in one launch
__global__ __launch_bounds__(256) void convt4_kernel(const float* __restrict__ wa,
                                                     const float* __restrict__ wb,
                                                     const float* __restrict__ wc,
                                                     const float* __restrict__ wd,
                                                     u16* __restrict__ da,
                                                     u16* __restrict__ db,
                                                     u16* __restrict__ dc,
                                                     u16* __restrict__ dd) {
    __shared__ float tile[32][33];
    int z = blockIdx.z;
    const float* w = (z == 0) ? wa : (z == 1) ? wb : (z == 2) ? wc : wd;
    u16* wt = (z == 0) ? da : (z == 1) ? db : (z == 2) ? dc : dd;
    int bn = blockIdx.x * 32, bk = blockIdx.y * 32;
    int tx = threadIdx.x & 31, ty = threadIdx.x >> 5;
#pragma unroll
    for (int i = 0; i < 4; i++)
        tile[ty + i * 8][tx] = w[(size_t)(bk + ty + i * 8) * 1024 + bn + tx];
    __syncthreads();
#pragma unroll
    for (int i = 0; i < 4; i++)
        wt[(size_t)(bn + ty + i * 8) * 1024 + bk + tx] = f2bf(tile[tx][ty + i * 8]);
}

// ---------------- V transpose (bf16): qkv V-part [b][s][1024] -> vT[b*1024+col][2048] ----------------
__global__ __launch_bounds__(256) void vtrans_kernel(const u16* __restrict__ qkv,
                                                     u16* __restrict__ vT) {
    __shared__ u16 tile[32][33];
    int bs = blockIdx.x * 32;
    int bc = blockIdx.y * 32;
    int b  = blockIdx.z;
    int tx = threadIdx.x & 31, ty = threadIdx.x >> 5;
#pragma unroll
    for (int i = 0; i < 4; i++)
        tile[ty + i * 8][tx] = qkv[(size_t)(b * 2048 + bs + ty + i * 8) * 3072 + 2048 + bc + tx];
    __syncthreads();
#pragma unroll
    for (int i = 0; i < 4; i++)
        vT[(size_t)(b * 1024 + bc + ty + i * 8) * 2048 + bs + tx] = tile[tx][ty + i * 8];
}

// ---------------- LayerNorm (fp32 in, bf16 out) ----------------
__global__ __launch_bounds__(256) void ln_kernel(const float* __restrict__ x,
                                                 const float* __restrict__ ga,
                                                 const float* __restrict__ gb,
                                                 u16* __restrict__ out) {
    int row = blockIdx.x;
    const float4* xr = (const float4*)(x + (size_t)row * 1024);
    float4 v = xr[threadIdx.x];
    float s  = v.x + v.y + v.z + v.w;
    float s2 = v.x * v.x + v.y * v.y + v.z * v.z + v.w * v.w;
#pragma unroll
    for (int off = 32; off; off >>= 1) {
        s  += __shfl_down(s, off);
        s2 += __shfl_down(s2, off);
    }
    __shared__ float rs[4], rs2[4];
    int wid = threadIdx.x >> 6, lane = threadIdx.x & 63;
    if (lane == 0) { rs[wid] = s; rs2[wid] = s2; }
    __syncthreads();
    float S  = rs[0] + rs[1] + rs[2] + rs[3];
    float S2 = rs2[0] + rs2[1] + rs2[2] + rs2[3];
    float mean = S * (1.0f / 1024.0f);
    float var  = fmaxf((S2 - 1024.0f * mean * mean) * (1.0f / 1023.0f), 0.0f);
    float scale = ga[0] / (sqrtf(var) + 1e-6f);
    float shift = gb[0] - mean * scale;
    u16 h0 = f2bf(v.x * scale + shift);
    u16 h1 = f2bf(v.y * scale + shift);
    u16 h2 = f2bf(v.z * scale + shift);
    u16 h3 = f2bf(v.w * scale + shift);
    uint2 pv;
    pv.x = (u32)h0 | ((u32)h1 << 16);
    pv.y = (u32)h2 | ((u32)h3 << 16);
    *(uint2*)(out + (size_t)row * 1024 + threadIdx.x * 4) = pv;
}

// ---------------- bias concat ----------------
__global__ __launch_bounds__(256) void bias3_kernel(const float* __restrict__ a,
                                                    const float* __restrict__ b,
                                                    const float* __restrict__ c,
                                                    float* __restrict__ d) {
    int i = blockIdx.x * 256 + threadIdx.x;
    float v = (i < 1024) ? a[i] : ((i < 2048) ? b[i - 1024] : c[i - 2048]);
    d[i] = v;
}

// ---------------- fused reduce: dst = dst + p + bias[col] + resid ----------------
__global__ __launch_bounds__(256) void addbias_kernel(float* __restrict__ dst,
                                                      const float* __restrict__ p,
                                                      const float* __restrict__ bias,
                                                      const float* __restrict__ resid) {
    int i4 = blockIdx.x * 256 + threadIdx.x;
    float4 d  = ((const float4*)dst)[i4];
    float4 pp = ((const float4*)p)[i4];
    float4 rr = ((const float4*)resid)[i4];
    float4 bb = *(const float4*)(bias + ((i4 * 4) & 1023));
    d.x += pp.x + bb.x + rr.x;
    d.y += pp.y + bb.y + rr.y;
    d.z += pp.z + bb.z + rr.z;
    d.w += pp.w + bb.w + rr.w;
    ((float4*)dst)[i4] = d;
}

// ---------------- fused reduce (2 partials): dst = dst + p0 + p1 + bias + resid ----------------
__global__ __launch_bounds__(256) void addbias2_kernel(float* __restrict__ dst,
                                                       const float* __restrict__ p0,
                                                       const float* __restrict__ p1,
                                                       const float* __restrict__ bias,
                                                       const float* __restrict__ resid) {
    int i4 = blockIdx.x * 256 + threadIdx.x;
    float4 d  = ((const float4*)dst)[i4];
    float4 pa = ((const float4*)p0)[i4];
    float4 pb = ((const float4*)p1)[i4];
    float4 rr = ((const float4*)resid)[i4];
    float4 bb = *(const float4*)(bias + ((i4 * 4) & 1023));
    d.x += pa.x + pb.x + bb.x + rr.x;
    d.y += pa.y + pb.y + bb.y + rr.y;
    d.z += pa.z + pb.z + bb.z + rr.z;
    d.w += pa.w + pb.w + bb.w + rr.w;
    ((float4*)dst)[i4] = d;
}

// ---------------- 256x256 8-wave GEMM, BK=64, 4-phase, swizzled LDS, counted vmcnt ----------------
template <int RELU>
__global__ __launch_bounds__(512) void gemm256_bt(const u16* __restrict__ A,
                                                  const u16* __restrict__ Bt,
                                                  const float* __restrict__ bias,
                                                  u16* __restrict__ C,
                                                  int M, int N, int K, int tilesN) {
    __shared__ u16 lds[2][2][16384];
    const int tid = threadIdx.x;
    const int lane = tid & 63, wid = tid >> 6;
    const int l15 = lane & 15, l4 = lane >> 4;
    const int wm = wid >> 2, wn = wid & 3;

    int nwg = gridDim.x;
    int bid = blockIdx.x;
    int swz = (bid & 7) * (nwg >> 3) + (bid >> 3);
    int ty = swz / tilesN, tx = swz % tilesN;

    const u16* Ag = A + (size_t)(ty * 256) * K;
    const u16* Bg = Bt + (size_t)(tx * 256) * K;

    auto stage_half = [&](int slot, int ab, int half, const u16* G, int k0) {
#pragma unroll
        for (int j = 0; j < 2; j++) {
            int off16 = half * 1024 + j * 512 + tid;
            int r = off16 >> 3;
            int gs = (off16 & 7) ^ (r & 7);
            const u16* src = G + (size_t)r * K + k0 + gs * 8;
            u16* dst = &lds[slot][ab][(size_t)(half * 1024 + j * 512 + (wid << 6)) * 8];
            async_load16(src, dst);
        }
    };

    f32x4 acc[8][4] = {};
    const int nT = K >> 6;

    stage_half(0, 0, 0, Ag, 0);
    stage_half(0, 0, 1, Ag, 0);
    stage_half(0, 1, 0, Bg, 0);
    stage_half(0, 1, 1, Bg, 0);
    __builtin_amdgcn_sched_barrier(0);

    for (int t = 0; t < nT; ++t) {
        const int cs = t & 1, ns = cs ^ 1;
        const int k1 = (t + 1) << 6;
        const bool pf = (t + 1 < nT);
#pragma unroll
        for (int ph = 0; ph < 4; ++ph) {
            if (ph == 0 && pf) { stage_half(ns, 0, 0, Ag, k1); stage_half(ns, 0, 1, Ag, k1); }
            if (ph == 1 && pf) { stage_half(ns, 1, 0, Bg, k1); stage_half(ns, 1, 1, Bg, k1); }
            __builtin_amdgcn_sched_barrier(0);
            if (ph == 0) {
                if (pf) asm volatile("s_waitcnt vmcnt(4)" ::: "memory");
                else    asm volatile("s_waitcnt vmcnt(0)" ::: "memory");
            }
            wg_barrier();

            const int rh = ph >> 1, ch = ph & 1;
            const u16* la = &lds[cs][0][0];
            const u16* lb = &lds[cs][1][0];
            short8 af[4][2], bf[2][2];
#pragma unroll
            for (int m2 = 0; m2 < 4; m2++) {
                int ra = wm * 128 + rh * 64 + m2 * 16 + l15;
#pragma unroll
                for (int ks = 0; ks < 2; ks++) {
                    int sl = (l4 + ks * 4) ^ (ra & 7);
                    af[m2][ks] = *(const short8*)&la[ra * 64 + sl * 8];
                }
            }
#pragma unroll
            for (int n2 = 0; n2 < 2; n2++) {
                int rb = wn * 64 + ch * 32 + n2 * 16 + l15;
#pragma unroll
                for (int ks = 0; ks < 2; ks++) {
                    int sl = (l4 + ks * 4) ^ (rb & 7);
                    bf[n2][ks] = *(const short8*)&lb[rb * 64 + sl * 8];
                }
            }
            __builtin_amdgcn_s_setprio(1);
#pragma unroll
            for (int m2 = 0; m2 < 4; m2++)
#pragma unroll
                for (int n2 = 0; n2 < 2; n2++)
#pragma unroll
                    for (int ks = 0; ks < 2; ks++)
                        acc[rh * 4 + m2][ch * 2 + n2] = __builtin_amdgcn_mfma_f32_16x16x32_bf16(
                            af[m2][ks], bf[n2][ks], acc[rh * 4 + m2][ch * 2 + n2], 0, 0, 0);
            __builtin_amdgcn_s_setprio(0);
            wg_barrier();
        }
    }

#pragma unroll
    for (int mi = 0; mi < 8; mi++) {
        int row0 = ty * 256 + wm * 128 + (mi >> 2) * 64 + (mi & 3) * 16 + l4 * 4;
#pragma unroll
        for (int ni = 0; ni < 4; ni++) {
            int col = tx * 256 + wn * 64 + (ni >> 1) * 32 + (ni & 1) * 16 + l15;
            float bc = bias[col];
#pragma unroll
            for (int jj = 0; jj < 4; jj++) {
                float v = acc[mi][ni][jj] + bc;
                if (RELU) v = fmaxf(v, 0.0f);
                C[(size_t)(row0 + jj) * N + col] = f2bf(v);
            }
        }
    }
}

// ---------------- bf16 GEMM, 2-phase double-buffered, split-K up to 3 ----------------
// MODE 2 split-K outputs: z==0 -> C0, z==last -> C1, middle -> Cp1 (all f32 partials).
template <int MODE, int RELU, int RESID>
__global__ __launch_bounds__(256) void gemm_bt(const u16* __restrict__ A,
                                               const u16* __restrict__ Bt,
                                               const float* __restrict__ bias,
                                               void* __restrict__ C0,
                                               void* __restrict__ C1,
                                               void* __restrict__ Cp1,
                                               const float* __restrict__ resid,
                                               int M, int N, int K, int kLen) {
    __shared__ u16 As[8192];
    __shared__ u16 Bs[8192];
    int tid = threadIdx.x, lane = tid & 63, wid = tid >> 6;
    int l15 = lane & 15, l4 = lane >> 4;
    int rowA0 = blockIdx.x * 128;
    int rowB0 = blockIdx.y * 128;
    int kOff = blockIdx.z * kLen;
    int len = K - kOff; if (len > kLen) len = kLen;
    void* Cout = (blockIdx.z == gridDim.z - 1) ? C1 : (blockIdx.z == 0 ? C0 : Cp1);
    int waveM = wid >> 1, waveN = wid & 1;

    int fl = tid * 8;
    int r0 = fl >> 5, c0 = fl & 31;
    const u16* gA0 = A + (size_t)(rowA0 + r0) * K + c0 + kOff;
    const u16* gA1 = A + (size_t)(rowA0 + 64 + r0) * K + c0 + kOff;
    const u16* gB0 = Bt + (size_t)(rowB0 + r0) * K + c0 + kOff;
    const u16* gB1 = Bt + (size_t)(rowB0 + 64 + r0) * K + c0 + kOff;

    f32x4 acc[4][4] = {};
    const int nIter = len >> 5;

    async_load16(gA0, As + wid * 512);
    async_load16(gA1, As + 2048 + wid * 512);
    async_load16(gB0, Bs + wid * 512);
    async_load16(gB1, Bs + 2048 + wid * 512);

    int cur = 0, kb = 32;
    for (int it = 0; it < nIter; ++it) {
        asm volatile("s_waitcnt vmcnt(0)" ::: "memory");
        __builtin_amdgcn_s_barrier();
        if (it + 1 < nIter) {
            u16* a = As + (cur ^ 1) * 4096;
            u16* bb = Bs + (cur ^ 1) * 4096;
            async_load16(gA0 + kb, a + wid * 512);
            async_load16(gA1 + kb, a + 2048 + wid * 512);
            async_load16(gB0 + kb, bb + wid * 512);
            async_load16(gB1 + kb, bb + 2048 + wid * 512);
        }
        __builtin_amdgcn_sched_barrier(0);

        const u16* a = As + cur * 4096;
        const u16* bb = Bs + cur * 4096;
        short8 af[4], bf[4];
#pragma unroll
        for (int m = 0; m < 4; m++)
            af[m] = *(const short8*)&a[(waveM * 64 + m * 16 + l15) * 32 + l4 * 8];
#pragma unroll
        for (int n = 0; n < 4; n++)
            bf[n] = *(const short8*)&bb[(waveN * 64 + n * 16 + l15) * 32 + l4 * 8];
#pragma unroll
        for (int m = 0; m < 4; m++)
#pragma unroll
            for (int n = 0; n < 4; n++)
                acc[m][n] = __builtin_amdgcn_mfma_f32_16x16x32_bf16(af[m], bf[n], acc[m][n], 0, 0, 0);

        __builtin_amdgcn_s_barrier();
        cur ^= 1;
        kb += 32;
    }

#pragma unroll
    for (int m = 0; m < 4; m++) {
        int row = rowA0 + waveM * 64 + m * 16 + l4 * 4;
#pragma unroll
        for (int n = 0; n < 4; n++) {
            int col = rowB0 + waveN * 64 + n * 16 + l15;
            float bc = (MODE == 2) ? 0.0f : bias[col];
#pragma unroll
            for (int j = 0; j < 4; j++) {
                float v = acc[m][n][j] + bc;
                if (RELU) v = fmaxf(v, 0.0f);
                if (RESID) v += resid[(size_t)(row + j) * N + col];
                if (MODE == 1)
                    ((u16*)Cout)[(size_t)(row + j) * N + col] = f2bf(v);
                else
                    ((float*)Cout)[(size_t)(row + j) * N + col] = v;
            }
        }
    }
}

// ---------------- flash attention v7: split-S, PT overlaid on dead Ks (LDS 38KB -> 4 blk/CU) ----------------
__global__ __launch_bounds__(512) void attn_kernel(const u16* __restrict__ qkv,
                                                   const u16* __restrict__ vT,
                                                   const int* __restrict__ mask,
                                                   u16* __restrict__ ctx) {
    const int S = 2048;
    const float C = 0.180336880f;  // 0.125 * log2(e)
    int qt = blockIdx.x;
    int bh = blockIdx.y;
    int b = bh >> 4, h = bh & 15;
    int tid = threadIdx.x;
    int wid = tid >> 6, lane = tid & 63;
    int l15 = lane & 15, l4 = lane >> 4;
    int g = wid >> 2, qw = wid & 3;

    __shared__ u16 Ks[2][64][72];   // QK^T operand; PT overlays after QK^T (barrier-protected)
    __shared__ u16 Vs[2][64][72];
    __shared__ float mbuf[2][4][16], lbuf[2][4][16];
    __shared__ int mflag;

    // per-wave PT slice inside Ks[g]: quarter of 9216B = 2304B = [16][36] u32
    u32* PTw = (u32*)&Ks[g][0][0] + qw * 576;

    if (tid == 0) mflag = 1;
    __syncthreads();
    {
        const int* mrow = mask + b * S;
        int ok = 1;
#pragma unroll
        for (int i = 0; i < 4; i++) ok &= (mrow[tid * 4 + i] != 0);
        if (!ok) mflag = 0;
    }

    int qrow0 = qt * 64 + qw * 16;
    const u16* qb = qkv + (size_t)(b * S + qrow0) * 3072 + h * 64;
    short8 qf0 = *(const short8*)(qb + (size_t)l15 * 3072 + l4 * 8);
    short8 qf1 = *(const short8*)(qb + (size_t)l15 * 3072 + 32 + l4 * 8);

    f32x4 o[4] = {};
    float m_i = -1e30f, lp = 0.0f;
    __syncthreads();
    const int allones = mflag;
    const int* mrow = mask + b * S;

    int tl = tid & 255;
    int srow = tl >> 3, c8 = (tl & 7) * 8;
    const int kt0 = g * 16;
    short8 kreg[2], vreg[2];
#pragma unroll
    for (int p = 0; p < 2; p++) {
        int r = p * 32 + srow;
        kreg[p] = *(const short8*)(qkv + (size_t)(b * S + kt0 * 64 + r) * 3072 + 1024 + h * 64 + c8);
        vreg[p] = *(const short8*)(vT + (size_t)(bh * 64 + r) * 2048 + kt0 * 64 + c8);
    }

    for (int it = 0; it < 16; ++it) {
        const int kt = kt0 + it;
        wg_barrier();  // (A) all waves done with prev iter's Ks(PT)/Vs reads
#pragma unroll
        for (int p = 0; p < 2; p++) {
            int r = p * 32 + srow;
            *(short8*)&Ks[g][r][c8] = kreg[p];
            *(short8*)&Vs[g][r][c8] = vreg[p];
        }
        if (it + 1 < 16) {
#pragma unroll
            for (int p = 0; p < 2; p++) {
                int r = p * 32 + srow;
                kreg[p] = *(const short8*)(qkv + (size_t)(b * S + (kt + 1) * 64 + r) * 3072 + 1024 + h * 64 + c8);
                vreg[p] = *(const short8*)(vT + (size_t)(bh * 64 + r) * 2048 + (kt + 1) * 64 + c8);
            }
        }
        asm volatile("s_waitcnt lgkmcnt(0)" ::: "memory");
        wg_barrier();  // (B) K/V staged

        // swapped QK^T: lane owns q = l15, s = kt*64 + kc*16 + l4*4 + j (raw scores)
        float sc[4][4];
#pragma unroll
        for (int kc = 0; kc < 4; kc++) {
            short8 kf0 = *(const short8*)&Ks[g][kc * 16 + l15][l4 * 8];
            short8 kf1 = *(const short8*)&Ks[g][kc * 16 + l15][32 + l4 * 8];
            f32x4 a = {};
            a = __builtin_amdgcn_mfma_f32_16x16x32_bf16(kf0, qf0, a, 0, 0, 0);
            a = __builtin_amdgcn_mfma_f32_16x16x32_bf16(kf1, qf1, a, 0, 0, 0);
            if (allones) {
#pragma unroll
                for (int j = 0; j < 4; j++) sc[kc][j] = a[j];
            } else {
#pragma unroll
                for (int j = 0; j < 4; j++) {
                    int mk = mrow[kt * 64 + kc * 16 + l4 * 4 + j];
                    sc[kc][j] = mk ? a[j] : -1e9f;
                }
            }
        }

        // deferred-max (raw threshold 64 = 8 nats)
        float lm = sc[0][0];
#pragma unroll
        for (int kc = 0; kc < 4; kc++)
#pragma unroll
            for (int j = 0; j < 4; j++) lm = fmaxf(lm, sc[kc][j]);
        if (!__all(lm <= m_i + 64.0f)) {
            float t = lm;
            t = fmaxf(t, __shfl_xor(t, 16));
            t = fmaxf(t, __shfl_xor(t, 32));
            float newm = fmaxf(m_i, t);
            float r = exp2fast((m_i - newm) * C);
            lp *= r;
            float rr0 = __shfl(r, l4 * 4 + 0);
            float rr1 = __shfl(r, l4 * 4 + 1);
            float rr2 = __shfl(r, l4 * 4 + 2);
            float rr3 = __shfl(r, l4 * 4 + 3);
#pragma unroll
            for (int dc = 0; dc < 4; dc++) {
                o[dc][0] *= rr0; o[dc][1] *= rr1; o[dc][2] *= rr2; o[dc][3] *= rr3;
            }
            m_i = newm;
        }

        // p = exp2(sc*C - m*C), packed pairs
        float nb = -m_i * C;
        u32 pk[4][2];
#pragma unroll
        for (int kc = 0; kc < 4; kc++) {
            float p0 = exp2fast(fmaf(sc[kc][0], C, nb));
            float p1 = exp2fast(fmaf(sc[kc][1], C, nb));
            float p2 = exp2fast(fmaf(sc[kc][2], C, nb));
            float p3 = exp2fast(fmaf(sc[kc][3], C, nb));
            lp += (p0 + p1) + (p2 + p3);
            pk[kc][0] = cvtpk(p0, p1);
            pk[kc][1] = cvtpk(p2, p3);
        }

        wg_barrier();  // (C) all waves done reading Ks -> safe to overlay PT

#pragma unroll
        for (int kc = 0; kc < 4; kc++) {
            uint2 w;
            w.x = pk[kc][0];
            w.y = pk[kc][1];
            *(uint2*)&PTw[l15 * 36 + kc * 8 + l4 * 2] = w;
        }

        uint2 r01 = *(const uint2*)&PTw[l15 * 36 + l4 * 4];
        uint2 r23 = *(const uint2*)&PTw[l15 * 36 + l4 * 4 + 2];
        uint2 r45 = *(const uint2*)&PTw[l15 * 36 + 16 + l4 * 4];
        uint2 r67 = *(const uint2*)&PTw[l15 * 36 + 16 + l4 * 4 + 2];
        u32x4 w0 = {r01.x, r01.y, r23.x, r23.y};
        u32x4 w1 = {r45.x, r45.y, r67.x, r67.y};
        short8 pa0 = __builtin_bit_cast(short8, w0);
        short8 pa1 = __builtin_bit_cast(short8, w1);

#pragma unroll
        for (int dc = 0; dc < 4; dc++) {
            short8 vf0 = *(const short8*)&Vs[g][dc * 16 + l15][l4 * 8];
            short8 vf1 = *(const short8*)&Vs[g][dc * 16 + l15][32 + l4 * 8];
            o[dc] = __builtin_amdgcn_mfma_f32_16x16x32_bf16(pa0, vf0, o[dc], 0, 0, 0);
            o[dc] = __builtin_amdgcn_mfma_f32_16x16x32_bf16(pa1, vf1, o[dc], 0, 0, 0);
        }
    }

    // -------- combine the two groups --------
    float lt = lp;
    lt += __shfl_xor(lt, 16);
    lt += __shfl_xor(lt, 32);
    if (l4 == 0) { mbuf[g][qw][l15] = m_i; lbuf[g][qw][l15] = lt; }
    __syncthreads();
    float mo = mbuf[g ^ 1][qw][l15], lo = lbuf[g ^ 1][qw][l15];
    float M  = fmaxf(m_i, mo);
    float rs = exp2fast((m_i - M) * C);
    float ro = exp2fast((mo - M) * C);
    float inv = 1.0f / (rs * lt + ro * lo);
    float rs_j[4], iv_j[4];
#pragma unroll
    for (int j = 0; j < 4; j++) {
        rs_j[j] = __shfl(rs,  l4 * 4 + j);
        iv_j[j] = __shfl(inv, l4 * 4 + j);
    }

    // exchange O halves via LDS (overlay on Ks, all reads done)
    float* obuf = (float*)&Ks[0][0][0];  // [2][4][16][32] floats = 16 KB (Ks total 18.4 KB)
#pragma unroll
    for (int c = 0; c < 2; c++) {
        int dce = (g ^ 1) * 2 + c;
#pragma unroll
        for (int j = 0; j < 4; j++)
            obuf[(((g * 4 + qw) * 16) + l4 * 4 + j) * 32 + c * 16 + l15] = o[dce][j] * rs_j[j];
    }
    __syncthreads();
#pragma unroll
    for (int c = 0; c < 2; c++) {
        int dco = g * 2 + c;
#pragma unroll
        for (int j = 0; j < 4; j++) {
            float peer = obuf[((((g ^ 1) * 4 + qw) * 16) + l4 * 4 + j) * 32 + c * 16 + l15];
            float val = (o[dco][j] * rs_j[j] + peer) * iv_j[j];
            int row = qrow0 + l4 * 4 + j;
            ctx[(size_t)(b * S + row) * 1024 + h * 64 + dco * 16 + l15] = f2bf(val);
        }
    }
}

// ---------------- launcher ----------------
extern "C" void kernel_launch(void* const* d_in, const int* in_sizes, int n_in,
                              void* d_out, int out_size, void* d_ws, size_t ws_size,
                              hipStream_t stream) {
    const float* x    = (const float*)d_in[0];
    const int*   mask = (const int*)d_in[1];
    const float* wq   = (const float*)d_in[2];
    const float* bq   = (const float*)d_in[3];
    const float* wk   = (const float*)d_in[4];
    const float* bk   = (const float*)d_in[5];
    const float* wv   = (const float*)d_in[6];
    const float* bv   = (const float*)d_in[7];
    const float* wo   = (const float*)d_in[8];
    const float* bo   = (const float*)d_in[9];
    const float* w1   = (const float*)d_in[10];
    const float* b1   = (const float*)d_in[11];
    const float* w2   = (const float*)d_in[12];
    const float* b2   = (const float*)d_in[13];
    const float* ln1a = (const float*)d_in[14];
    const float* ln1b = (const float*)d_in[15];
    const float* ln2a = (const float*)d_in[16];
    const float* ln2b = (const float*)d_in[17];
    float* out = (float*)d_out;

    char* ws = (char*)d_ws;
    u16*   wqkvt = (u16*)(ws + 0);            //  6 MB
    u16*   wot   = (u16*)(ws + 6291456);      //  2 MB
    u16*   w1t   = (u16*)(ws + 8388608);      //  8 MB
    u16*   w2t   = (u16*)(ws + 16777216);     //  8 MB
    float* bqkv  = (float*)(ws + 25165824);   // 12 KB
    char*  regA  = ws + 26214400;
    u16*   xn1   = (u16*)(regA + 0);          //  8 MB
    u16*   vT    = (u16*)(regA + 0);          //  8 MB (aliases xn1)
    u16*   qkv   = (u16*)(regA + 8388608);    // 24 MB
    u16*   ctx   = (u16*)(regA + 33554432);   //  8 MB
    float* p0wo  = (float*)(regA + 0);        // 16 MB (vT+qkv dead by WO time)
    float* p1wo  = (float*)(regA + 16777216); // 16 MB (rest of qkv region)
    float* x1    = (float*)(ws + 68157440);   // 16 MB
    u16*   xn2   = (u16*)(regA + 0);          //  8 MB (partials dead after reduce)
    u16*   ff1   = (u16*)(regA + 8388608);    // 32 MB
    float* p0f2  = (float*)(ws + 0);          // 16 MB (weights dead by FFN2 time)

    dim3 blk(256);

    convt4_kernel<<<dim3(32, 32, 4), blk, 0, stream>>>(
        wq, wk, wv, wo, wqkvt, wqkvt + 1024 * 1024, wqkvt + 2048 * 1024, wot);
    convt_kernel<<<dim3(128, 32), blk, 0, stream>>>(w1, w1t, 1024, 4096);
    convt_kernel<<<dim3(32, 128), blk, 0, stream>>>(w2, w2t, 4096, 1024);
    bias3_kernel<<<dim3(12), blk, 0, stream>>>(bq, bk, bv, bqkv);

    // LN1 -> QKV (256^2 8-wave) -> attn -> WO (split-K=3) + reduce(+bo+x)
    ln_kernel<<<dim3(4096), blk, 0, stream>>>(x, ln1a, ln1b, xn1);
    gemm256_bt<0><<<dim3(192), dim3(512), 0, stream>>>(xn1, wqkvt, bqkv, qkv, 4096, 3072, 1024, 12);
    vtrans_kernel<<<dim3(64, 32, 2), blk, 0, stream>>>(qkv, vT);
    attn_kernel<<<dim3(32, 32), dim3(512), 0, stream>>>(qkv, vT, mask, ctx);
    gemm_bt<2, 0, 0><<<dim3(32, 8, 3), blk, 0, stream>>>(ctx, wot, nullptr, p0wo, x1, p1wo,
                                                         nullptr, 4096, 1024, 1024, 352);
    addbias2_kernel<<<dim3(4096), blk, 0, stream>>>(x1, p0wo, p1wo, bo, x);

    // LN2 -> FFN1 (256^2 8-wave, relu) -> FFN2 (split-K=2) + reduce(+b2+x1)
    ln_kernel<<<dim3(4096), blk, 0, stream>>>(x1, ln2a, ln2b, xn2);
    gemm256_bt<1><<<dim3(256), dim3(512), 0, stream>>>(xn2, w1t, b1, ff1, 4096, 4096, 1024, 16);
    gemm_bt<2, 0, 0><<<dim3(32, 8, 2), blk, 0, stream>>>(ff1, w2t, nullptr, p0f2, out, nullptr,
                                                         nullptr, 4096, 1024, 4096, 2048);
    addbias_kernel<<<dim3(4096), blk, 0, stream>>>(out, p0f2, b2, x1);
}

// Round 9
// 274.848 us; speedup vs baseline: 1.0179x; 1.0179x over previous
//
#include <hip/hip_runtime.h>
#include <hip/hip_bf16.h>

typedef __attribute__((ext_vector_type(8))) short short8;
typedef __attribute__((ext_vector_type(4))) float f32x4;
typedef __attribute__((ext_vector_type(4))) unsigned int u32x4;
using u16 = unsigned short;
typedef unsigned int u32;

__device__ __forceinline__ u16 f2bf(float f) {
    u32 u = __builtin_bit_cast(u32, f);
    u32 r = u + 0x7FFFu + ((u >> 16) & 1u);
    return (u16)(r >> 16);
}

__device__ __forceinline__ float exp2fast(float x) {
    return __builtin_amdgcn_exp2f(x);  // v_exp_f32
}

__device__ __forceinline__ u32 cvtpk(float lo, float hi) {
    u32 r;
    asm("v_cvt_pk_bf16_f32 %0, %1, %2" : "=v"(r) : "v"(lo), "v"(hi));
    return r;
}

__device__ __forceinline__ void async_load16(const void* g, void* l) {
    __builtin_amdgcn_global_load_lds(
        (const __attribute__((address_space(1))) void*)g,
        (__attribute__((address_space(3))) void*)l, 16, 0, 0);
}

__device__ __forceinline__ void wg_barrier() {
    asm volatile("" ::: "memory");
    __builtin_amdgcn_s_barrier();
    asm volatile("" ::: "memory");
}

// ---------------- weight transpose + f32->bf16 convert: w[K][N] -> wt[N][K] ----------------
__global__ __launch_bounds__(256) void convt_kernel(const float* __restrict__ w,
                                                    u16* __restrict__ wt, int K, int N) {
    __shared__ float tile[32][33];
    int bn = blockIdx.x * 32, bk = blockIdx.y * 32;
    int tx = threadIdx.x & 31, ty = threadIdx.x >> 5;
#pragma unroll
    for (int i = 0; i < 4; i++)
        tile[ty + i * 8][tx] = w[(size_t)(bk + ty + i * 8) * N + bn + tx];
    __syncthreads();
#pragma unroll
    for (int i = 0; i < 4; i++)
        wt[(size_t)(bn + ty + i * 8) * K + bk + tx] = f2bf(tile[tx][ty + i * 8]);
}

// 4 square 1024x1024 transposes in one launch
__global__ __launch_bounds__(256) void convt4_kernel(const float* __restrict__ wa,
                                                     const float* __restrict__ wb,
                                                     const float* __restrict__ wc,
                                                     const float* __restrict__ wd,
                                                     u16* __restrict__ da,
                                                     u16* __restrict__ db,
                                                     u16* __restrict__ dc,
                                                     u16* __restrict__ dd) {
    __shared__ float tile[32][33];
    int z = blockIdx.z;
    const float* w = (z == 0) ? wa : (z == 1) ? wb : (z == 2) ? wc : wd;
    u16* wt = (z == 0) ? da : (z == 1) ? db : (z == 2) ? dc : dd;
    int bn = blockIdx.x * 32, bk = blockIdx.y * 32;
    int tx = threadIdx.x & 31, ty = threadIdx.x >> 5;
#pragma unroll
    for (int i = 0; i < 4; i++)
        tile[ty + i * 8][tx] = w[(size_t)(bk + ty + i * 8) * 1024 + bn + tx];
    __syncthreads();
#pragma unroll
    for (int i = 0; i < 4; i++)
        wt[(size_t)(bn + ty + i * 8) * 1024 + bk + tx] = f2bf(tile[tx][ty + i * 8]);
}

// ---------------- V transpose (bf16): qkv V-part [b][s][1024] -> vT[b*1024+col][2048] ----------------
__global__ __launch_bounds__(256) void vtrans_kernel(const u16* __restrict__ qkv,
                                                     u16* __restrict__ vT) {
    __shared__ u16 tile[32][33];
    int bs = blockIdx.x * 32;
    int bc = blockIdx.y * 32;
    int b  = blockIdx.z;
    int tx = threadIdx.x & 31, ty = threadIdx.x >> 5;
#pragma unroll
    for (int i = 0; i < 4; i++)
        tile[ty + i * 8][tx] = qkv[(size_t)(b * 2048 + bs + ty + i * 8) * 3072 + 2048 + bc + tx];
    __syncthreads();
#pragma unroll
    for (int i = 0; i < 4; i++)
        vT[(size_t)(b * 1024 + bc + ty + i * 8) * 2048 + bs + tx] = tile[tx][ty + i * 8];
}

// ---------------- LayerNorm (fp32 in, bf16 out) ----------------
__global__ __launch_bounds__(256) void ln_kernel(const float* __restrict__ x,
                                                 const float* __restrict__ ga,
                                                 const float* __restrict__ gb,
                                                 u16* __restrict__ out) {
    int row = blockIdx.x;
    const float4* xr = (const float4*)(x + (size_t)row * 1024);
    float4 v = xr[threadIdx.x];
    float s  = v.x + v.y + v.z + v.w;
    float s2 = v.x * v.x + v.y * v.y + v.z * v.z + v.w * v.w;
#pragma unroll
    for (int off = 32; off; off >>= 1) {
        s  += __shfl_down(s, off);
        s2 += __shfl_down(s2, off);
    }
    __shared__ float rs[4], rs2[4];
    int wid = threadIdx.x >> 6, lane = threadIdx.x & 63;
    if (lane == 0) { rs[wid] = s; rs2[wid] = s2; }
    __syncthreads();
    float S  = rs[0] + rs[1] + rs[2] + rs[3];
    float S2 = rs2[0] + rs2[1] + rs2[2] + rs2[3];
    float mean = S * (1.0f / 1024.0f);
    float var  = fmaxf((S2 - 1024.0f * mean * mean) * (1.0f / 1023.0f), 0.0f);
    float scale = ga[0] / (sqrtf(var) + 1e-6f);
    float shift = gb[0] - mean * scale;
    u16 h0 = f2bf(v.x * scale + shift);
    u16 h1 = f2bf(v.y * scale + shift);
    u16 h2 = f2bf(v.z * scale + shift);
    u16 h3 = f2bf(v.w * scale + shift);
    uint2 pv;
    pv.x = (u32)h0 | ((u32)h1 << 16);
    pv.y = (u32)h2 | ((u32)h3 << 16);
    *(uint2*)(out + (size_t)row * 1024 + threadIdx.x * 4) = pv;
}

// ---------------- bias concat ----------------
__global__ __launch_bounds__(256) void bias3_kernel(const float* __restrict__ a,
                                                    const float* __restrict__ b,
                                                    const float* __restrict__ c,
                                                    float* __restrict__ d) {
    int i = blockIdx.x * 256 + threadIdx.x;
    float v = (i < 1024) ? a[i] : ((i < 2048) ? b[i - 1024] : c[i - 2048]);
    d[i] = v;
}

// ---------------- fused reduce: dst = dst + p + bias[col] + resid ----------------
__global__ __launch_bounds__(256) void addbias_kernel(float* __restrict__ dst,
                                                      const float* __restrict__ p,
                                                      const float* __restrict__ bias,
                                                      const float* __restrict__ resid) {
    int i4 = blockIdx.x * 256 + threadIdx.x;
    float4 d  = ((const float4*)dst)[i4];
    float4 pp = ((const float4*)p)[i4];
    float4 rr = ((const float4*)resid)[i4];
    float4 bb = *(const float4*)(bias + ((i4 * 4) & 1023));
    d.x += pp.x + bb.x + rr.x;
    d.y += pp.y + bb.y + rr.y;
    d.z += pp.z + bb.z + rr.z;
    d.w += pp.w + bb.w + rr.w;
    ((float4*)dst)[i4] = d;
}

// ---------------- 256x256 8-wave GEMM, BK=64, 4-phase, swizzled LDS, counted vmcnt ----------------
template <int RELU>
__global__ __launch_bounds__(512) void gemm256_bt(const u16* __restrict__ A,
                                                  const u16* __restrict__ Bt,
                                                  const float* __restrict__ bias,
                                                  u16* __restrict__ C,
                                                  int M, int N, int K, int tilesN) {
    __shared__ u16 lds[2][2][16384];
    const int tid = threadIdx.x;
    const int lane = tid & 63, wid = tid >> 6;
    const int l15 = lane & 15, l4 = lane >> 4;
    const int wm = wid >> 2, wn = wid & 3;

    int nwg = gridDim.x;
    int bid = blockIdx.x;
    int swz = (bid & 7) * (nwg >> 3) + (bid >> 3);
    int ty = swz / tilesN, tx = swz % tilesN;

    const u16* Ag = A + (size_t)(ty * 256) * K;
    const u16* Bg = Bt + (size_t)(tx * 256) * K;

    auto stage_half = [&](int slot, int ab, int half, const u16* G, int k0) {
#pragma unroll
        for (int j = 0; j < 2; j++) {
            int off16 = half * 1024 + j * 512 + tid;
            int r = off16 >> 3;
            int gs = (off16 & 7) ^ (r & 7);
            const u16* src = G + (size_t)r * K + k0 + gs * 8;
            u16* dst = &lds[slot][ab][(size_t)(half * 1024 + j * 512 + (wid << 6)) * 8];
            async_load16(src, dst);
        }
    };

    f32x4 acc[8][4] = {};
    const int nT = K >> 6;

    stage_half(0, 0, 0, Ag, 0);
    stage_half(0, 0, 1, Ag, 0);
    stage_half(0, 1, 0, Bg, 0);
    stage_half(0, 1, 1, Bg, 0);
    __builtin_amdgcn_sched_barrier(0);

    for (int t = 0; t < nT; ++t) {
        const int cs = t & 1, ns = cs ^ 1;
        const int k1 = (t + 1) << 6;
        const bool pf = (t + 1 < nT);
#pragma unroll
        for (int ph = 0; ph < 4; ++ph) {
            if (ph == 0 && pf) { stage_half(ns, 0, 0, Ag, k1); stage_half(ns, 0, 1, Ag, k1); }
            if (ph == 1 && pf) { stage_half(ns, 1, 0, Bg, k1); stage_half(ns, 1, 1, Bg, k1); }
            __builtin_amdgcn_sched_barrier(0);
            if (ph == 0) {
                if (pf) asm volatile("s_waitcnt vmcnt(4)" ::: "memory");
                else    asm volatile("s_waitcnt vmcnt(0)" ::: "memory");
            }
            wg_barrier();

            const int rh = ph >> 1, ch = ph & 1;
            const u16* la = &lds[cs][0][0];
            const u16* lb = &lds[cs][1][0];
            short8 af[4][2], bf[2][2];
#pragma unroll
            for (int m2 = 0; m2 < 4; m2++) {
                int ra = wm * 128 + rh * 64 + m2 * 16 + l15;
#pragma unroll
                for (int ks = 0; ks < 2; ks++) {
                    int sl = (l4 + ks * 4) ^ (ra & 7);
                    af[m2][ks] = *(const short8*)&la[ra * 64 + sl * 8];
                }
            }
#pragma unroll
            for (int n2 = 0; n2 < 2; n2++) {
                int rb = wn * 64 + ch * 32 + n2 * 16 + l15;
#pragma unroll
                for (int ks = 0; ks < 2; ks++) {
                    int sl = (l4 + ks * 4) ^ (rb & 7);
                    bf[n2][ks] = *(const short8*)&lb[rb * 64 + sl * 8];
                }
            }
            __builtin_amdgcn_s_setprio(1);
#pragma unroll
            for (int m2 = 0; m2 < 4; m2++)
#pragma unroll
                for (int n2 = 0; n2 < 2; n2++)
#pragma unroll
                    for (int ks = 0; ks < 2; ks++)
                        acc[rh * 4 + m2][ch * 2 + n2] = __builtin_amdgcn_mfma_f32_16x16x32_bf16(
                            af[m2][ks], bf[n2][ks], acc[rh * 4 + m2][ch * 2 + n2], 0, 0, 0);
            __builtin_amdgcn_s_setprio(0);
            wg_barrier();
        }
    }

#pragma unroll
    for (int mi = 0; mi < 8; mi++) {
        int row0 = ty * 256 + wm * 128 + (mi >> 2) * 64 + (mi & 3) * 16 + l4 * 4;
#pragma unroll
        for (int ni = 0; ni < 4; ni++) {
            int col = tx * 256 + wn * 64 + (ni >> 1) * 32 + (ni & 1) * 16 + l15;
            float bc = bias[col];
#pragma unroll
            for (int jj = 0; jj < 4; jj++) {
                float v = acc[mi][ni][jj] + bc;
                if (RELU) v = fmaxf(v, 0.0f);
                C[(size_t)(row0 + jj) * N + col] = f2bf(v);
            }
        }
    }
}

// ---------------- bf16 GEMM, 2-phase double-buffered, split-K up to 3 ----------------
template <int MODE, int RELU, int RESID>
__global__ __launch_bounds__(256) void gemm_bt(const u16* __restrict__ A,
                                               const u16* __restrict__ Bt,
                                               const float* __restrict__ bias,
                                               void* __restrict__ C0,
                                               void* __restrict__ C1,
                                               void* __restrict__ Cp1,
                                               const float* __restrict__ resid,
                                               int M, int N, int K, int kLen) {
    __shared__ u16 As[8192];
    __shared__ u16 Bs[8192];
    int tid = threadIdx.x, lane = tid & 63, wid = tid >> 6;
    int l15 = lane & 15, l4 = lane >> 4;
    int rowA0 = blockIdx.x * 128;
    int rowB0 = blockIdx.y * 128;
    int kOff = blockIdx.z * kLen;
    int len = K - kOff; if (len > kLen) len = kLen;
    void* Cout = (blockIdx.z == gridDim.z - 1) ? C1 : (blockIdx.z == 0 ? C0 : Cp1);
    int waveM = wid >> 1, waveN = wid & 1;

    int fl = tid * 8;
    int r0 = fl >> 5, c0 = fl & 31;
    const u16* gA0 = A + (size_t)(rowA0 + r0) * K + c0 + kOff;
    const u16* gA1 = A + (size_t)(rowA0 + 64 + r0) * K + c0 + kOff;
    const u16* gB0 = Bt + (size_t)(rowB0 + r0) * K + c0 + kOff;
    const u16* gB1 = Bt + (size_t)(rowB0 + 64 + r0) * K + c0 + kOff;

    f32x4 acc[4][4] = {};
    const int nIter = len >> 5;

    async_load16(gA0, As + wid * 512);
    async_load16(gA1, As + 2048 + wid * 512);
    async_load16(gB0, Bs + wid * 512);
    async_load16(gB1, Bs + 2048 + wid * 512);

    int cur = 0, kb = 32;
    for (int it = 0; it < nIter; ++it) {
        asm volatile("s_waitcnt vmcnt(0)" ::: "memory");
        __builtin_amdgcn_s_barrier();
        if (it + 1 < nIter) {
            u16* a = As + (cur ^ 1) * 4096;
            u16* bb = Bs + (cur ^ 1) * 4096;
            async_load16(gA0 + kb, a + wid * 512);
            async_load16(gA1 + kb, a + 2048 + wid * 512);
            async_load16(gB0 + kb, bb + wid * 512);
            async_load16(gB1 + kb, bb + 2048 + wid * 512);
        }
        __builtin_amdgcn_sched_barrier(0);

        const u16* a = As + cur * 4096;
        const u16* bb = Bs + cur * 4096;
        short8 af[4], bf[4];
#pragma unroll
        for (int m = 0; m < 4; m++)
            af[m] = *(const short8*)&a[(waveM * 64 + m * 16 + l15) * 32 + l4 * 8];
#pragma unroll
        for (int n = 0; n < 4; n++)
            bf[n] = *(const short8*)&bb[(waveN * 64 + n * 16 + l15) * 32 + l4 * 8];
#pragma unroll
        for (int m = 0; m < 4; m++)
#pragma unroll
            for (int n = 0; n < 4; n++)
                acc[m][n] = __builtin_amdgcn_mfma_f32_16x16x32_bf16(af[m], bf[n], acc[m][n], 0, 0, 0);

        __builtin_amdgcn_s_barrier();
        cur ^= 1;
        kb += 32;
    }

#pragma unroll
    for (int m = 0; m < 4; m++) {
        int row = rowA0 + waveM * 64 + m * 16 + l4 * 4;
#pragma unroll
        for (int n = 0; n < 4; n++) {
            int col = rowB0 + waveN * 64 + n * 16 + l15;
            float bc = (MODE == 2) ? 0.0f : bias[col];
#pragma unroll
            for (int j = 0; j < 4; j++) {
                float v = acc[m][n][j] + bc;
                if (RELU) v = fmaxf(v, 0.0f);
                if (RESID) v += resid[(size_t)(row + j) * N + col];
                if (MODE == 1)
                    ((u16*)Cout)[(size_t)(row + j) * N + col] = f2bf(v);
                else
                    ((float*)Cout)[(size_t)(row + j) * N + col] = v;
            }
        }
    }
}

// ---------------- flash attention v8: split-S, KVBLK=32, LDS 38KB (4 blocks/CU) ----------------
// 8 waves: group g = wid>>2 handles s in [g*1024, g*1024+1024) in 32 tiles of 32; qw = wid&3.
__global__ __launch_bounds__(512) void attn_kernel(const u16* __restrict__ qkv,
                                                   const u16* __restrict__ vT,
                                                   const int* __restrict__ mask,
                                                   u16* __restrict__ ctx) {
    const int S = 2048;
    const float C = 0.180336880f;  // 0.125 * log2(e)
    int qt = blockIdx.x;
    int bh = blockIdx.y;
    int b = bh >> 4, h = bh & 15;
    int tid = threadIdx.x;
    int wid = tid >> 6, lane = tid & 63;
    int l15 = lane & 15, l4 = lane >> 4;
    int g = wid >> 2, qw = wid & 3;

    // K tiles: [g][32 s][72], V tiles: [g][64 d][40]; contiguous for final obuf overlay
    __shared__ unsigned char KVraw[2 * 32 * 72 * 2 + 2 * 64 * 40 * 2];  // 9216 + 10240 B
    u16 (*Kts)[32][72] = (u16(*)[32][72])KVraw;
    u16 (*Vts)[64][40] = (u16(*)[64][40])(KVraw + 9216);
    __shared__ u32 PT[8][16][36];
    __shared__ float mbuf[2][4][16], lbuf[2][4][16];
    __shared__ int mflag;

    if (tid == 0) mflag = 1;
    __syncthreads();
    {
        const int* mrow = mask + b * S;
        int ok = 1;
#pragma unroll
        for (int i = 0; i < 4; i++) ok &= (mrow[tid * 4 + i] != 0);
        if (!ok) mflag = 0;
    }

    int qrow0 = qt * 64 + qw * 16;
    const u16* qb = qkv + (size_t)(b * S + qrow0) * 3072 + h * 64;
    short8 qf0 = *(const short8*)(qb + (size_t)l15 * 3072 + l4 * 8);
    short8 qf1 = *(const short8*)(qb + (size_t)l15 * 3072 + 32 + l4 * 8);

    f32x4 o[4] = {};
    float m_i = -1e30f, lp = 0.0f;
    __syncthreads();
    const int allones = mflag;
    const int* mrow = mask + b * S;

    // staging coords (group-local 256 threads): K: 32 rows x 64 cols; V: 64 rows x 32 cols
    int tl = tid & 255;
    int srow = tl >> 3, c8 = (tl & 7) * 8;    // K
    int vrow = tl >> 2, vc8 = (tl & 3) * 8;   // V
    const int kt0 = g * 32;
    short8 kreg, vreg;
    kreg = *(const short8*)(qkv + (size_t)(b * S + kt0 * 32 + srow) * 3072 + 1024 + h * 64 + c8);
    vreg = *(const short8*)(vT + (size_t)(bh * 64 + vrow) * 2048 + kt0 * 32 + vc8);

    for (int it = 0; it < 32; ++it) {
        const int kt = kt0 + it;
        wg_barrier();  // (A) all waves done with prev tile reads
        *(short8*)&Kts[g][srow][c8] = kreg;
        *(short8*)&Vts[g][vrow][vc8] = vreg;
        if (it + 1 < 32) {
            kreg = *(const short8*)(qkv + (size_t)(b * S + (kt + 1) * 32 + srow) * 3072 + 1024 + h * 64 + c8);
            vreg = *(const short8*)(vT + (size_t)(bh * 64 + vrow) * 2048 + (kt + 1) * 32 + vc8);
        }
        asm volatile("s_waitcnt lgkmcnt(0)" ::: "memory");
        wg_barrier();  // (B) staged

        // swapped QK^T: lane owns q = l15, s = kt*32 + kc*16 + l4*4 + j (raw scores)
        float sc[2][4];
#pragma unroll
        for (int kc = 0; kc < 2; kc++) {
            short8 kf0 = *(const short8*)&Kts[g][kc * 16 + l15][l4 * 8];
            short8 kf1 = *(const short8*)&Kts[g][kc * 16 + l15][32 + l4 * 8];
            f32x4 a = {};
            a = __builtin_amdgcn_mfma_f32_16x16x32_bf16(kf0, qf0, a, 0, 0, 0);
            a = __builtin_amdgcn_mfma_f32_16x16x32_bf16(kf1, qf1, a, 0, 0, 0);
            if (allones) {
#pragma unroll
                for (int j = 0; j < 4; j++) sc[kc][j] = a[j];
            } else {
#pragma unroll
                for (int j = 0; j < 4; j++) {
                    int mk = mrow[kt * 32 + kc * 16 + l4 * 4 + j];
                    sc[kc][j] = mk ? a[j] : -1e9f;
                }
            }
        }

        // deferred-max (raw threshold 64 = 8 nats)
        float lm = fmaxf(fmaxf(fmaxf(sc[0][0], sc[0][1]), fmaxf(sc[0][2], sc[0][3])),
                         fmaxf(fmaxf(sc[1][0], sc[1][1]), fmaxf(sc[1][2], sc[1][3])));
        if (!__all(lm <= m_i + 64.0f)) {
            float t = lm;
            t = fmaxf(t, __shfl_xor(t, 16));
            t = fmaxf(t, __shfl_xor(t, 32));
            float newm = fmaxf(m_i, t);
            float r = exp2fast((m_i - newm) * C);
            lp *= r;
            float rr0 = __shfl(r, l4 * 4 + 0);
            float rr1 = __shfl(r, l4 * 4 + 1);
            float rr2 = __shfl(r, l4 * 4 + 2);
            float rr3 = __shfl(r, l4 * 4 + 3);
#pragma unroll
            for (int dc = 0; dc < 4; dc++) {
                o[dc][0] *= rr0; o[dc][1] *= rr1; o[dc][2] *= rr2; o[dc][3] *= rr3;
            }
            m_i = newm;
        }

        // p = exp2(sc*C - m*C); pack pairs; 2x ds_write_b64 into per-wave PT
        float nb = -m_i * C;
#pragma unroll
        for (int kc = 0; kc < 2; kc++) {
            float p0 = exp2fast(fmaf(sc[kc][0], C, nb));
            float p1 = exp2fast(fmaf(sc[kc][1], C, nb));
            float p2 = exp2fast(fmaf(sc[kc][2], C, nb));
            float p3 = exp2fast(fmaf(sc[kc][3], C, nb));
            lp += (p0 + p1) + (p2 + p3);
            uint2 w;
            w.x = cvtpk(p0, p1);
            w.y = cvtpk(p2, p3);
            *(uint2*)&PT[wid][l15][kc * 8 + l4 * 2] = w;
        }

        // A-frag: lane needs P[q=l15][s-local = l4*8 + 0..7] -> words l4*4 + 0..3
        uint2 r01 = *(const uint2*)&PT[wid][l15][l4 * 4];
        uint2 r23 = *(const uint2*)&PT[wid][l15][l4 * 4 + 2];
        u32x4 w0 = {r01.x, r01.y, r23.x, r23.y};
        short8 pa0 = __builtin_bit_cast(short8, w0);

#pragma unroll
        for (int dc = 0; dc < 4; dc++) {
            short8 vf0 = *(const short8*)&Vts[g][dc * 16 + l15][l4 * 8];
            o[dc] = __builtin_amdgcn_mfma_f32_16x16x32_bf16(pa0, vf0, o[dc], 0, 0, 0);
        }
    }

    // -------- combine the two groups --------
    float lt = lp;
    lt += __shfl_xor(lt, 16);
    lt += __shfl_xor(lt, 32);
    if (l4 == 0) { mbuf[g][qw][l15] = m_i; lbuf[g][qw][l15] = lt; }
    __syncthreads();
    float mo = mbuf[g ^ 1][qw][l15], lo = lbuf[g ^ 1][qw][l15];
    float M  = fmaxf(m_i, mo);
    float rs = exp2fast((m_i - M) * C);
    float ro = exp2fast((mo - M) * C);
    float inv = 1.0f / (rs * lt + ro * lo);
    float rs_j[4], iv_j[4];
#pragma unroll
    for (int j = 0; j < 4; j++) {
        rs_j[j] = __shfl(rs,  l4 * 4 + j);
        iv_j[j] = __shfl(inv, l4 * 4 + j);
    }

    // exchange O halves via LDS (overlay on KVraw, all reads done)
    float* obuf = (float*)KVraw;  // [2][4][16][32] floats = 16 KB <= 19.4 KB
#pragma unroll
    for (int c = 0; c < 2; c++) {
        int dce = (g ^ 1) * 2 + c;
#pragma unroll
        for (int j = 0; j < 4; j++)
            obuf[(((g * 4 + qw) * 16) + l4 * 4 + j) * 32 + c * 16 + l15] = o[dce][j] * rs_j[j];
    }
    __syncthreads();
#pragma unroll
    for (int c = 0; c < 2; c++) {
        int dco = g * 2 + c;
#pragma unroll
        for (int j = 0; j < 4; j++) {
            float peer = obuf[((((g ^ 1) * 4 + qw) * 16) + l4 * 4 + j) * 32 + c * 16 + l15];
            float val = (o[dco][j] * rs_j[j] + peer) * iv_j[j];
            int row = qrow0 + l4 * 4 + j;
            ctx[(size_t)(b * S + row) * 1024 + h * 64 + dco * 16 + l15] = f2bf(val);
        }
    }
}

// ---------------- launcher ----------------
extern "C" void kernel_launch(void* const* d_in, const int* in_sizes, int n_in,
                              void* d_out, int out_size, void* d_ws, size_t ws_size,
                              hipStream_t stream) {
    const float* x    = (const float*)d_in[0];
    const int*   mask = (const int*)d_in[1];
    const float* wq   = (const float*)d_in[2];
    const float* bq   = (const float*)d_in[3];
    const float* wk   = (const float*)d_in[4];
    const float* bk   = (const float*)d_in[5];
    const float* wv   = (const float*)d_in[6];
    const float* bv   = (const float*)d_in[7];
    const float* wo   = (const float*)d_in[8];
    const float* bo   = (const float*)d_in[9];
    const float* w1   = (const float*)d_in[10];
    const float* b1   = (const float*)d_in[11];
    const float* w2   = (const float*)d_in[12];
    const float* b2   = (const float*)d_in[13];
    const float* ln1a = (const float*)d_in[14];
    const float* ln1b = (const float*)d_in[15];
    const float* ln2a = (const float*)d_in[16];
    const float* ln2b = (const float*)d_in[17];
    float* out = (float*)d_out;

    char* ws = (char*)d_ws;
    u16*   wqkvt = (u16*)(ws + 0);            //  6 MB
    u16*   wot   = (u16*)(ws + 6291456);      //  2 MB
    u16*   w1t   = (u16*)(ws + 8388608);      //  8 MB
    u16*   w2t   = (u16*)(ws + 16777216);     //  8 MB
    float* bqkv  = (float*)(ws + 25165824);   // 12 KB
    char*  regA  = ws + 26214400;
    u16*   xn1   = (u16*)(regA + 0);          //  8 MB
    u16*   vT    = (u16*)(regA + 0);          //  8 MB (aliases xn1)
    u16*   qkv   = (u16*)(regA + 8388608);    // 24 MB
    u16*   ctx   = (u16*)(regA + 33554432);   //  8 MB
    float* p0wo  = (float*)(regA + 0);        // 16 MB (vT+qkv dead by WO time)
    float* x1    = (float*)(ws + 68157440);   // 16 MB
    u16*   xn2   = (u16*)(regA + 0);          //  8 MB
    u16*   ff1   = (u16*)(regA + 8388608);    // 32 MB
    float* p0f2  = (float*)(ws + 0);          // 16 MB (weights dead by FFN2 time)

    dim3 blk(256);

    convt4_kernel<<<dim3(32, 32, 4), blk, 0, stream>>>(
        wq, wk, wv, wo, wqkvt, wqkvt + 1024 * 1024, wqkvt + 2048 * 1024, wot);
    convt_kernel<<<dim3(128, 32), blk, 0, stream>>>(w1, w1t, 1024, 4096);
    convt_kernel<<<dim3(32, 128), blk, 0, stream>>>(w2, w2t, 4096, 1024);
    bias3_kernel<<<dim3(12), blk, 0, stream>>>(bq, bk, bv, bqkv);

    // LN1 -> QKV (256^2 8-wave) -> attn -> WO (split-K=2) + reduce(+bo+x)
    ln_kernel<<<dim3(4096), blk, 0, stream>>>(x, ln1a, ln1b, xn1);
    gemm256_bt<0><<<dim3(192), dim3(512), 0, stream>>>(xn1, wqkvt, bqkv, qkv, 4096, 3072, 1024, 12);
    vtrans_kernel<<<dim3(64, 32, 2), blk, 0, stream>>>(qkv, vT);
    attn_kernel<<<dim3(32, 32), dim3(512), 0, stream>>>(qkv, vT, mask, ctx);
    gemm_bt<2, 0, 0><<<dim3(32, 8, 2), blk, 0, stream>>>(ctx, wot, nullptr, p0wo, x1, nullptr,
                                                         nullptr, 4096, 1024, 1024, 512);
    addbias_kernel<<<dim3(4096), blk, 0, stream>>>(x1, p0wo, bo, x);

    // LN2 -> FFN1 (256^2 8-wave, relu) -> FFN2 (split-K=2) + reduce(+b2+x1)
    ln_kernel<<<dim3(4096), blk, 0, stream>>>(x1, ln2a, ln2b, xn2);
    gemm256_bt<1><<<dim3(256), dim3(512), 0, stream>>>(xn2, w1t, b1, ff1, 4096, 4096, 1024, 16);
    gemm_bt<2, 0, 0><<<dim3(32, 8, 2), blk, 0, stream>>>(ff1, w2t, nullptr, p0f2, out, nullptr,
                                                         nullptr, 4096, 1024, 4096, 2048);
    addbias_kernel<<<dim3(4096), blk, 0, stream>>>(out, p0f2, b2, x1);
}

// Round 10
// 271.251 us; speedup vs baseline: 1.0314x; 1.0133x over previous
//
#include <hip/hip_runtime.h>
#include <hip/hip_bf16.h>

typedef __attribute__((ext_vector_type(8))) short short8;
typedef __attribute__((ext_vector_type(4))) float f32x4;
typedef __attribute__((ext_vector_type(4))) unsigned int u32x4;
using u16 = unsigned short;
typedef unsigned int u32;

__device__ __forceinline__ u16 f2bf(float f) {
    u32 u = __builtin_bit_cast(u32, f);
    u32 r = u + 0x7FFFu + ((u >> 16) & 1u);
    return (u16)(r >> 16);
}

__device__ __forceinline__ float exp2fast(float x) {
    return __builtin_amdgcn_exp2f(x);  // v_exp_f32
}

__device__ __forceinline__ u32 cvtpk(float lo, float hi) {
    u32 r;
    asm("v_cvt_pk_bf16_f32 %0, %1, %2" : "=v"(r) : "v"(lo), "v"(hi));
    return r;
}

__device__ __forceinline__ void async_load16(const void* g, void* l) {
    __builtin_amdgcn_global_load_lds(
        (const __attribute__((address_space(1))) void*)g,
        (__attribute__((address_space(3))) void*)l, 16, 0, 0);
}

__device__ __forceinline__ void wg_barrier() {
    asm volatile("" ::: "memory");
    __builtin_amdgcn_s_barrier();
    asm volatile("" ::: "memory");
}

// ---------------- weight transpose + f32->bf16 convert: w[K][N] -> wt[N][K] ----------------
__global__ __launch_bounds__(256) void convt_kernel(const float* __restrict__ w,
                                                    u16* __restrict__ wt, int K, int N) {
    __shared__ float tile[32][33];
    int bn = blockIdx.x * 32, bk = blockIdx.y * 32;
    int tx = threadIdx.x & 31, ty = threadIdx.x >> 5;
#pragma unroll
    for (int i = 0; i < 4; i++)
        tile[ty + i * 8][tx] = w[(size_t)(bk + ty + i * 8) * N + bn + tx];
    __syncthreads();
#pragma unroll
    for (int i = 0; i < 4; i++)
        wt[(size_t)(bn + ty + i * 8) * K + bk + tx] = f2bf(tile[tx][ty + i * 8]);
}

// 4 square 1024x1024 transposes in one launch
__global__ __launch_bounds__(256) void convt4_kernel(const float* __restrict__ wa,
                                                     const float* __restrict__ wb,
                                                     const float* __restrict__ wc,
                                                     const float* __restrict__ wd,
                                                     u16* __restrict__ da,
                                                     u16* __restrict__ db,
                                                     u16* __restrict__ dc,
                                                     u16* __restrict__ dd) {
    __shared__ float tile[32][33];
    int z = blockIdx.z;
    const float* w = (z == 0) ? wa : (z == 1) ? wb : (z == 2) ? wc : wd;
    u16* wt = (z == 0) ? da : (z == 1) ? db : (z == 2) ? dc : dd;
    int bn = blockIdx.x * 32, bk = blockIdx.y * 32;
    int tx = threadIdx.x & 31, ty = threadIdx.x >> 5;
#pragma unroll
    for (int i = 0; i < 4; i++)
        tile[ty + i * 8][tx] = w[(size_t)(bk + ty + i * 8) * 1024 + bn + tx];
    __syncthreads();
#pragma unroll
    for (int i = 0; i < 4; i++)
        wt[(size_t)(bn + ty + i * 8) * 1024 + bk + tx] = f2bf(tile[tx][ty + i * 8]);
}

// ---------------- V transpose (bf16): qkv V-part [b][s][1024] -> vT[b*1024+col][2048] ----------------
__global__ __launch_bounds__(256) void vtrans_kernel(const u16* __restrict__ qkv,
                                                     u16* __restrict__ vT) {
    __shared__ u16 tile[32][33];
    int bs = blockIdx.x * 32;
    int bc = blockIdx.y * 32;
    int b  = blockIdx.z;
    int tx = threadIdx.x & 31, ty = threadIdx.x >> 5;
#pragma unroll
    for (int i = 0; i < 4; i++)
        tile[ty + i * 8][tx] = qkv[(size_t)(b * 2048 + bs + ty + i * 8) * 3072 + 2048 + bc + tx];
    __syncthreads();
#pragma unroll
    for (int i = 0; i < 4; i++)
        vT[(size_t)(b * 1024 + bc + ty + i * 8) * 2048 + bs + tx] = tile[tx][ty + i * 8];
}

// ---------------- LayerNorm (fp32 in, bf16 out) ----------------
__global__ __launch_bounds__(256) void ln_kernel(const float* __restrict__ x,
                                                 const float* __restrict__ ga,
                                                 const float* __restrict__ gb,
                                                 u16* __restrict__ out) {
    int row = blockIdx.x;
    const float4* xr = (const float4*)(x + (size_t)row * 1024);
    float4 v = xr[threadIdx.x];
    float s  = v.x + v.y + v.z + v.w;
    float s2 = v.x * v.x + v.y * v.y + v.z * v.z + v.w * v.w;
#pragma unroll
    for (int off = 32; off; off >>= 1) {
        s  += __shfl_down(s, off);
        s2 += __shfl_down(s2, off);
    }
    __shared__ float rs[4], rs2[4];
    int wid = threadIdx.x >> 6, lane = threadIdx.x & 63;
    if (lane == 0) { rs[wid] = s; rs2[wid] = s2; }
    __syncthreads();
    float S  = rs[0] + rs[1] + rs[2] + rs[3];
    float S2 = rs2[0] + rs2[1] + rs2[2] + rs2[3];
    float mean = S * (1.0f / 1024.0f);
    float var  = fmaxf((S2 - 1024.0f * mean * mean) * (1.0f / 1023.0f), 0.0f);
    float scale = ga[0] / (sqrtf(var) + 1e-6f);
    float shift = gb[0] - mean * scale;
    u16 h0 = f2bf(v.x * scale + shift);
    u16 h1 = f2bf(v.y * scale + shift);
    u16 h2 = f2bf(v.z * scale + shift);
    u16 h3 = f2bf(v.w * scale + shift);
    uint2 pv;
    pv.x = (u32)h0 | ((u32)h1 << 16);
    pv.y = (u32)h2 | ((u32)h3 << 16);
    *(uint2*)(out + (size_t)row * 1024 + threadIdx.x * 4) = pv;
}

// ---------------- bias concat ----------------
__global__ __launch_bounds__(256) void bias3_kernel(const float* __restrict__ a,
                                                    const float* __restrict__ b,
                                                    const float* __restrict__ c,
                                                    float* __restrict__ d) {
    int i = blockIdx.x * 256 + threadIdx.x;
    float v = (i < 1024) ? a[i] : ((i < 2048) ? b[i - 1024] : c[i - 2048]);
    d[i] = v;
}

// ---------------- fused reduce: dst = dst + p + bias[col] + resid ----------------
__global__ __launch_bounds__(256) void addbias_kernel(float* __restrict__ dst,
                                                      const float* __restrict__ p,
                                                      const float* __restrict__ bias,
                                                      const float* __restrict__ resid) {
    int i4 = blockIdx.x * 256 + threadIdx.x;
    float4 d  = ((const float4*)dst)[i4];
    float4 pp = ((const float4*)p)[i4];
    float4 rr = ((const float4*)resid)[i4];
    float4 bb = *(const float4*)(bias + ((i4 * 4) & 1023));
    d.x += pp.x + bb.x + rr.x;
    d.y += pp.y + bb.y + rr.y;
    d.z += pp.z + bb.z + rr.z;
    d.w += pp.w + bb.w + rr.w;
    ((float4*)dst)[i4] = d;
}

// ---- fused reduce (2 partials) + LayerNorm: x1 = dst+p0+p1+bias+resid; xn = LN(x1) bf16 ----
// one block per row of 1024 (grid 4096 x 256 thr)
__global__ __launch_bounds__(256) void addbias2_ln_kernel(float* __restrict__ dst,
                                                          const float* __restrict__ p0,
                                                          const float* __restrict__ p1,
                                                          const float* __restrict__ bias,
                                                          const float* __restrict__ resid,
                                                          const float* __restrict__ ga,
                                                          const float* __restrict__ gb,
                                                          u16* __restrict__ xn) {
    int row = blockIdx.x;
    int i4 = row * 256 + threadIdx.x;
    float4 d  = ((const float4*)dst)[i4];
    float4 pa = ((const float4*)p0)[i4];
    float4 pb = ((const float4*)p1)[i4];
    float4 rr = ((const float4*)resid)[i4];
    float4 bb = *(const float4*)(bias + threadIdx.x * 4);
    d.x += pa.x + pb.x + bb.x + rr.x;
    d.y += pa.y + pb.y + bb.y + rr.y;
    d.z += pa.z + pb.z + bb.z + rr.z;
    d.w += pa.w + pb.w + bb.w + rr.w;
    ((float4*)dst)[i4] = d;

    // row LayerNorm over the 1024 values
    float s  = d.x + d.y + d.z + d.w;
    float s2 = d.x * d.x + d.y * d.y + d.z * d.z + d.w * d.w;
#pragma unroll
    for (int off = 32; off; off >>= 1) {
        s  += __shfl_down(s, off);
        s2 += __shfl_down(s2, off);
    }
    __shared__ float rs[4], rs2[4];
    int wid = threadIdx.x >> 6, lane = threadIdx.x & 63;
    if (lane == 0) { rs[wid] = s; rs2[wid] = s2; }
    __syncthreads();
    float S  = rs[0] + rs[1] + rs[2] + rs[3];
    float S2 = rs2[0] + rs2[1] + rs2[2] + rs2[3];
    float mean = S * (1.0f / 1024.0f);
    float var  = fmaxf((S2 - 1024.0f * mean * mean) * (1.0f / 1023.0f), 0.0f);
    float scale = ga[0] / (sqrtf(var) + 1e-6f);
    float shift = gb[0] - mean * scale;
    uint2 pv;
    pv.x = (u32)f2bf(d.x * scale + shift) | ((u32)f2bf(d.y * scale + shift) << 16);
    pv.y = (u32)f2bf(d.z * scale + shift) | ((u32)f2bf(d.w * scale + shift) << 16);
    *(uint2*)(xn + (size_t)row * 1024 + threadIdx.x * 4) = pv;
}

// ---------------- 256x256 8-wave GEMM, BK=64, 4-phase, swizzled LDS, counted vmcnt ----------------
template <int RELU>
__global__ __launch_bounds__(512) void gemm256_bt(const u16* __restrict__ A,
                                                  const u16* __restrict__ Bt,
                                                  const float* __restrict__ bias,
                                                  u16* __restrict__ C,
                                                  int M, int N, int K, int tilesN) {
    __shared__ u16 lds[2][2][16384];
    const int tid = threadIdx.x;
    const int lane = tid & 63, wid = tid >> 6;
    const int l15 = lane & 15, l4 = lane >> 4;
    const int wm = wid >> 2, wn = wid & 3;

    int nwg = gridDim.x;
    int bid = blockIdx.x;
    int swz = (bid & 7) * (nwg >> 3) + (bid >> 3);
    int ty = swz / tilesN, tx = swz % tilesN;

    const u16* Ag = A + (size_t)(ty * 256) * K;
    const u16* Bg = Bt + (size_t)(tx * 256) * K;

    auto stage_half = [&](int slot, int ab, int half, const u16* G, int k0) {
#pragma unroll
        for (int j = 0; j < 2; j++) {
            int off16 = half * 1024 + j * 512 + tid;
            int r = off16 >> 3;
            int gs = (off16 & 7) ^ (r & 7);
            const u16* src = G + (size_t)r * K + k0 + gs * 8;
            u16* dst = &lds[slot][ab][(size_t)(half * 1024 + j * 512 + (wid << 6)) * 8];
            async_load16(src, dst);
        }
    };

    f32x4 acc[8][4] = {};
    const int nT = K >> 6;

    stage_half(0, 0, 0, Ag, 0);
    stage_half(0, 0, 1, Ag, 0);
    stage_half(0, 1, 0, Bg, 0);
    stage_half(0, 1, 1, Bg, 0);
    __builtin_amdgcn_sched_barrier(0);

    for (int t = 0; t < nT; ++t) {
        const int cs = t & 1, ns = cs ^ 1;
        const int k1 = (t + 1) << 6;
        const bool pf = (t + 1 < nT);
#pragma unroll
        for (int ph = 0; ph < 4; ++ph) {
            if (ph == 0 && pf) { stage_half(ns, 0, 0, Ag, k1); stage_half(ns, 0, 1, Ag, k1); }
            if (ph == 1 && pf) { stage_half(ns, 1, 0, Bg, k1); stage_half(ns, 1, 1, Bg, k1); }
            __builtin_amdgcn_sched_barrier(0);
            if (ph == 0) {
                if (pf) asm volatile("s_waitcnt vmcnt(4)" ::: "memory");
                else    asm volatile("s_waitcnt vmcnt(0)" ::: "memory");
            }
            wg_barrier();

            const int rh = ph >> 1, ch = ph & 1;
            const u16* la = &lds[cs][0][0];
            const u16* lb = &lds[cs][1][0];
            short8 af[4][2], bf[2][2];
#pragma unroll
            for (int m2 = 0; m2 < 4; m2++) {
                int ra = wm * 128 + rh * 64 + m2 * 16 + l15;
#pragma unroll
                for (int ks = 0; ks < 2; ks++) {
                    int sl = (l4 + ks * 4) ^ (ra & 7);
                    af[m2][ks] = *(const short8*)&la[ra * 64 + sl * 8];
                }
            }
#pragma unroll
            for (int n2 = 0; n2 < 2; n2++) {
                int rb = wn * 64 + ch * 32 + n2 * 16 + l15;
#pragma unroll
                for (int ks = 0; ks < 2; ks++) {
                    int sl = (l4 + ks * 4) ^ (rb & 7);
                    bf[n2][ks] = *(const short8*)&lb[rb * 64 + sl * 8];
                }
            }
            __builtin_amdgcn_s_setprio(1);
#pragma unroll
            for (int m2 = 0; m2 < 4; m2++)
#pragma unroll
                for (int n2 = 0; n2 < 2; n2++)
#pragma unroll
                    for (int ks = 0; ks < 2; ks++)
                        acc[rh * 4 + m2][ch * 2 + n2] = __builtin_amdgcn_mfma_f32_16x16x32_bf16(
                            af[m2][ks], bf[n2][ks], acc[rh * 4 + m2][ch * 2 + n2], 0, 0, 0);
            __builtin_amdgcn_s_setprio(0);
            wg_barrier();
        }
    }

#pragma unroll
    for (int mi = 0; mi < 8; mi++) {
        int row0 = ty * 256 + wm * 128 + (mi >> 2) * 64 + (mi & 3) * 16 + l4 * 4;
#pragma unroll
        for (int ni = 0; ni < 4; ni++) {
            int col = tx * 256 + wn * 64 + (ni >> 1) * 32 + (ni & 1) * 16 + l15;
            float bc = bias[col];
#pragma unroll
            for (int jj = 0; jj < 4; jj++) {
                float v = acc[mi][ni][jj] + bc;
                if (RELU) v = fmaxf(v, 0.0f);
                C[(size_t)(row0 + jj) * N + col] = f2bf(v);
            }
        }
    }
}

// ---------------- bf16 GEMM, 2-phase double-buffered, split-K up to 3 ----------------
template <int MODE, int RELU, int RESID>
__global__ __launch_bounds__(256) void gemm_bt(const u16* __restrict__ A,
                                               const u16* __restrict__ Bt,
                                               const float* __restrict__ bias,
                                               void* __restrict__ C0,
                                               void* __restrict__ C1,
                                               void* __restrict__ Cp1,
                                               const float* __restrict__ resid,
                                               int M, int N, int K, int kLen) {
    __shared__ u16 As[8192];
    __shared__ u16 Bs[8192];
    int tid = threadIdx.x, lane = tid & 63, wid = tid >> 6;
    int l15 = lane & 15, l4 = lane >> 4;
    int rowA0 = blockIdx.x * 128;
    int rowB0 = blockIdx.y * 128;
    int kOff = blockIdx.z * kLen;
    int len = K - kOff; if (len > kLen) len = kLen;
    void* Cout = (blockIdx.z == gridDim.z - 1) ? C1 : (blockIdx.z == 0 ? C0 : Cp1);
    int waveM = wid >> 1, waveN = wid & 1;

    int fl = tid * 8;
    int r0 = fl >> 5, c0 = fl & 31;
    const u16* gA0 = A + (size_t)(rowA0 + r0) * K + c0 + kOff;
    const u16* gA1 = A + (size_t)(rowA0 + 64 + r0) * K + c0 + kOff;
    const u16* gB0 = Bt + (size_t)(rowB0 + r0) * K + c0 + kOff;
    const u16* gB1 = Bt + (size_t)(rowB0 + 64 + r0) * K + c0 + kOff;

    f32x4 acc[4][4] = {};
    const int nIter = len >> 5;

    async_load16(gA0, As + wid * 512);
    async_load16(gA1, As + 2048 + wid * 512);
    async_load16(gB0, Bs + wid * 512);
    async_load16(gB1, Bs + 2048 + wid * 512);

    int cur = 0, kb = 32;
    for (int it = 0; it < nIter; ++it) {
        asm volatile("s_waitcnt vmcnt(0)" ::: "memory");
        __builtin_amdgcn_s_barrier();
        if (it + 1 < nIter) {
            u16* a = As + (cur ^ 1) * 4096;
            u16* bb = Bs + (cur ^ 1) * 4096;
            async_load16(gA0 + kb, a + wid * 512);
            async_load16(gA1 + kb, a + 2048 + wid * 512);
            async_load16(gB0 + kb, bb + wid * 512);
            async_load16(gB1 + kb, bb + 2048 + wid * 512);
        }
        __builtin_amdgcn_sched_barrier(0);

        const u16* a = As + cur * 4096;
        const u16* bb = Bs + cur * 4096;
        short8 af[4], bf[4];
#pragma unroll
        for (int m = 0; m < 4; m++)
            af[m] = *(const short8*)&a[(waveM * 64 + m * 16 + l15) * 32 + l4 * 8];
#pragma unroll
        for (int n = 0; n < 4; n++)
            bf[n] = *(const short8*)&bb[(waveN * 64 + n * 16 + l15) * 32 + l4 * 8];
#pragma unroll
        for (int m = 0; m < 4; m++)
#pragma unroll
            for (int n = 0; n < 4; n++)
                acc[m][n] = __builtin_amdgcn_mfma_f32_16x16x32_bf16(af[m], bf[n], acc[m][n], 0, 0, 0);

        __builtin_amdgcn_s_barrier();
        cur ^= 1;
        kb += 32;
    }

#pragma unroll
    for (int m = 0; m < 4; m++) {
        int row = rowA0 + waveM * 64 + m * 16 + l4 * 4;
#pragma unroll
        for (int n = 0; n < 4; n++) {
            int col = rowB0 + waveN * 64 + n * 16 + l15;
            float bc = (MODE == 2) ? 0.0f : bias[col];
#pragma unroll
            for (int j = 0; j < 4; j++) {
                float v = acc[m][n][j] + bc;
                if (RELU) v = fmaxf(v, 0.0f);
                if (RESID) v += resid[(size_t)(row + j) * N + col];
                if (MODE == 1)
                    ((u16*)Cout)[(size_t)(row + j) * N + col] = f2bf(v);
                else
                    ((float*)Cout)[(size_t)(row + j) * N + col] = v;
            }
        }
    }
}

// ---------------- flash attention v6 (measured best): 8-wave split-S, PT-LDS P relayout ----------------
__global__ __launch_bounds__(512) void attn_kernel(const u16* __restrict__ qkv,
                                                   const u16* __restrict__ vT,
                                                   const int* __restrict__ mask,
                                                   u16* __restrict__ ctx) {
    const int S = 2048;
    const float C = 0.180336880f;  // 0.125 * log2(e)
    int qt = blockIdx.x;
    int bh = blockIdx.y;
    int b = bh >> 4, h = bh & 15;
    int tid = threadIdx.x;
    int wid = tid >> 6, lane = tid & 63;
    int l15 = lane & 15, l4 = lane >> 4;
    int g = wid >> 2, qw = wid & 3;

    __shared__ u16 Ks[2][64][72];
    __shared__ u16 Vs[2][64][72];
    __shared__ u32 PT[8][16][38];
    __shared__ float mbuf[2][4][16], lbuf[2][4][16];
    __shared__ int mflag;

    if (tid == 0) mflag = 1;
    __syncthreads();
    {
        const int* mrow = mask + b * S;
        int ok = 1;
#pragma unroll
        for (int i = 0; i < 4; i++) ok &= (mrow[tid * 4 + i] != 0);
        if (!ok) mflag = 0;
    }

    int qrow0 = qt * 64 + qw * 16;
    const u16* qb = qkv + (size_t)(b * S + qrow0) * 3072 + h * 64;
    short8 qf0 = *(const short8*)(qb + (size_t)l15 * 3072 + l4 * 8);
    short8 qf1 = *(const short8*)(qb + (size_t)l15 * 3072 + 32 + l4 * 8);

    f32x4 o[4] = {};
    float m_i = -1e30f, lp = 0.0f;
    __syncthreads();
    const int allones = mflag;
    const int* mrow = mask + b * S;

    int tl = tid & 255;
    int srow = tl >> 3, c8 = (tl & 7) * 8;
    const int kt0 = g * 16;
    short8 kreg[2], vreg[2];
#pragma unroll
    for (int p = 0; p < 2; p++) {
        int r = p * 32 + srow;
        kreg[p] = *(const short8*)(qkv + (size_t)(b * S + kt0 * 64 + r) * 3072 + 1024 + h * 64 + c8);
        vreg[p] = *(const short8*)(vT + (size_t)(bh * 64 + r) * 2048 + kt0 * 64 + c8);
    }

    for (int it = 0; it < 16; ++it) {
        const int kt = kt0 + it;
        wg_barrier();
#pragma unroll
        for (int p = 0; p < 2; p++) {
            int r = p * 32 + srow;
            *(short8*)&Ks[g][r][c8] = kreg[p];
            *(short8*)&Vs[g][r][c8] = vreg[p];
        }
        if (it + 1 < 16) {
#pragma unroll
            for (int p = 0; p < 2; p++) {
                int r = p * 32 + srow;
                kreg[p] = *(const short8*)(qkv + (size_t)(b * S + (kt + 1) * 64 + r) * 3072 + 1024 + h * 64 + c8);
                vreg[p] = *(const short8*)(vT + (size_t)(bh * 64 + r) * 2048 + (kt + 1) * 64 + c8);
            }
        }
        asm volatile("s_waitcnt lgkmcnt(0)" ::: "memory");
        wg_barrier();

        float sc[4][4];
#pragma unroll
        for (int kc = 0; kc < 4; kc++) {
            short8 kf0 = *(const short8*)&Ks[g][kc * 16 + l15][l4 * 8];
            short8 kf1 = *(const short8*)&Ks[g][kc * 16 + l15][32 + l4 * 8];
            f32x4 a = {};
            a = __builtin_amdgcn_mfma_f32_16x16x32_bf16(kf0, qf0, a, 0, 0, 0);
            a = __builtin_amdgcn_mfma_f32_16x16x32_bf16(kf1, qf1, a, 0, 0, 0);
            if (allones) {
#pragma unroll
                for (int j = 0; j < 4; j++) sc[kc][j] = a[j];
            } else {
#pragma unroll
                for (int j = 0; j < 4; j++) {
                    int mk = mrow[kt * 64 + kc * 16 + l4 * 4 + j];
                    sc[kc][j] = mk ? a[j] : -1e9f;
                }
            }
        }

        float lm = sc[0][0];
#pragma unroll
        for (int kc = 0; kc < 4; kc++)
#pragma unroll
            for (int j = 0; j < 4; j++) lm = fmaxf(lm, sc[kc][j]);
        if (!__all(lm <= m_i + 64.0f)) {
            float t = lm;
            t = fmaxf(t, __shfl_xor(t, 16));
            t = fmaxf(t, __shfl_xor(t, 32));
            float newm = fmaxf(m_i, t);
            float r = exp2fast((m_i - newm) * C);
            lp *= r;
            float rr0 = __shfl(r, l4 * 4 + 0);
            float rr1 = __shfl(r, l4 * 4 + 1);
            float rr2 = __shfl(r, l4 * 4 + 2);
            float rr3 = __shfl(r, l4 * 4 + 3);
#pragma unroll
            for (int dc = 0; dc < 4; dc++) {
                o[dc][0] *= rr0; o[dc][1] *= rr1; o[dc][2] *= rr2; o[dc][3] *= rr3;
            }
            m_i = newm;
        }

        float nb = -m_i * C;
#pragma unroll
        for (int kc = 0; kc < 4; kc++) {
            float p0 = exp2fast(fmaf(sc[kc][0], C, nb));
            float p1 = exp2fast(fmaf(sc[kc][1], C, nb));
            float p2 = exp2fast(fmaf(sc[kc][2], C, nb));
            float p3 = exp2fast(fmaf(sc[kc][3], C, nb));
            lp += (p0 + p1) + (p2 + p3);
            uint2 w;
            w.x = cvtpk(p0, p1);
            w.y = cvtpk(p2, p3);
            *(uint2*)&PT[wid][l15][kc * 8 + l4 * 2] = w;
        }

        uint2 r01 = *(const uint2*)&PT[wid][l15][l4 * 4];
        uint2 r23 = *(const uint2*)&PT[wid][l15][l4 * 4 + 2];
        uint2 r45 = *(const uint2*)&PT[wid][l15][16 + l4 * 4];
        uint2 r67 = *(const uint2*)&PT[wid][l15][16 + l4 * 4 + 2];
        u32x4 w0 = {r01.x, r01.y, r23.x, r23.y};
        u32x4 w1 = {r45.x, r45.y, r67.x, r67.y};
        short8 pa0 = __builtin_bit_cast(short8, w0);
        short8 pa1 = __builtin_bit_cast(short8, w1);

#pragma unroll
        for (int dc = 0; dc < 4; dc++) {
            short8 vf0 = *(const short8*)&Vs[g][dc * 16 + l15][l4 * 8];
            short8 vf1 = *(const short8*)&Vs[g][dc * 16 + l15][32 + l4 * 8];
            o[dc] = __builtin_amdgcn_mfma_f32_16x16x32_bf16(pa0, vf0, o[dc], 0, 0, 0);
            o[dc] = __builtin_amdgcn_mfma_f32_16x16x32_bf16(pa1, vf1, o[dc], 0, 0, 0);
        }
    }

    // -------- combine the two groups --------
    float lt = lp;
    lt += __shfl_xor(lt, 16);
    lt += __shfl_xor(lt, 32);
    if (l4 == 0) { mbuf[g][qw][l15] = m_i; lbuf[g][qw][l15] = lt; }
    __syncthreads();
    float mo = mbuf[g ^ 1][qw][l15], lo = lbuf[g ^ 1][qw][l15];
    float M  = fmaxf(m_i, mo);
    float rs = exp2fast((m_i - M) * C);
    float ro = exp2fast((mo - M) * C);
    float inv = 1.0f / (rs * lt + ro * lo);
    float rs_j[4], iv_j[4];
#pragma unroll
    for (int j = 0; j < 4; j++) {
        rs_j[j] = __shfl(rs,  l4 * 4 + j);
        iv_j[j] = __shfl(inv, l4 * 4 + j);
    }

    float* obuf = (float*)&Ks[0][0][0];  // 16 KB overlay on dead Ks
#pragma unroll
    for (int c = 0; c < 2; c++) {
        int dce = (g ^ 1) * 2 + c;
#pragma unroll
        for (int j = 0; j < 4; j++)
            obuf[(((g * 4 + qw) * 16) + l4 * 4 + j) * 32 + c * 16 + l15] = o[dce][j] * rs_j[j];
    }
    __syncthreads();
#pragma unroll
    for (int c = 0; c < 2; c++) {
        int dco = g * 2 + c;
#pragma unroll
        for (int j = 0; j < 4; j++) {
            float peer = obuf[((((g ^ 1) * 4 + qw) * 16) + l4 * 4 + j) * 32 + c * 16 + l15];
            float val = (o[dco][j] * rs_j[j] + peer) * iv_j[j];
            int row = qrow0 + l4 * 4 + j;
            ctx[(size_t)(b * S + row) * 1024 + h * 64 + dco * 16 + l15] = f2bf(val);
        }
    }
}

// ---------------- launcher ----------------
extern "C" void kernel_launch(void* const* d_in, const int* in_sizes, int n_in,
                              void* d_out, int out_size, void* d_ws, size_t ws_size,
                              hipStream_t stream) {
    const float* x    = (const float*)d_in[0];
    const int*   mask = (const int*)d_in[1];
    const float* wq   = (const float*)d_in[2];
    const float* bq   = (const float*)d_in[3];
    const float* wk   = (const float*)d_in[4];
    const float* bk   = (const float*)d_in[5];
    const float* wv   = (const float*)d_in[6];
    const float* bv   = (const float*)d_in[7];
    const float* wo   = (const float*)d_in[8];
    const float* bo   = (const float*)d_in[9];
    const float* w1   = (const float*)d_in[10];
    const float* b1   = (const float*)d_in[11];
    const float* w2   = (const float*)d_in[12];
    const float* b2   = (const float*)d_in[13];
    const float* ln1a = (const float*)d_in[14];
    const float* ln1b = (const float*)d_in[15];
    const float* ln2a = (const float*)d_in[16];
    const float* ln2b = (const float*)d_in[17];
    float* out = (float*)d_out;

    char* ws = (char*)d_ws;
    u16*   wqkvt = (u16*)(ws + 0);            //  6 MB
    u16*   wot   = (u16*)(ws + 6291456);      //  2 MB
    u16*   w1t   = (u16*)(ws + 8388608);      //  8 MB
    u16*   w2t   = (u16*)(ws + 16777216);     //  8 MB
    float* bqkv  = (float*)(ws + 25165824);   // 12 KB
    char*  regA  = ws + 26214400;
    u16*   xn1   = (u16*)(regA + 0);          //  8 MB
    u16*   vT    = (u16*)(regA + 0);          //  8 MB (aliases xn1)
    u16*   qkv   = (u16*)(regA + 8388608);    // 24 MB
    u16*   ctx   = (u16*)(regA + 33554432);   //  8 MB
    float* p0wo  = (float*)(regA + 0);        // 16 MB (vT+qkv dead by WO time)
    float* p1wo  = (float*)(regA + 16777216); // 16 MB
    float* x1    = (float*)(ws + 68157440);   // 16 MB
    u16*   xn2   = (u16*)(regA + 0);          //  8 MB (partials dead after reduce)
    u16*   ff1   = (u16*)(regA + 8388608);    // 32 MB
    float* p0f2  = (float*)(ws + 0);          // 16 MB (weights dead by FFN2 time)

    dim3 blk(256);

    convt4_kernel<<<dim3(32, 32, 4), blk, 0, stream>>>(
        wq, wk, wv, wo, wqkvt, wqkvt + 1024 * 1024, wqkvt + 2048 * 1024, wot);
    convt_kernel<<<dim3(128, 32), blk, 0, stream>>>(w1, w1t, 1024, 4096);
    convt_kernel<<<dim3(32, 128), blk, 0, stream>>>(w2, w2t, 4096, 1024);
    bias3_kernel<<<dim3(12), blk, 0, stream>>>(bq, bk, bv, bqkv);

    // LN1 -> QKV (256^2 8-wave) -> attn -> WO (split-K=3) + fused reduce+bo+x+LN2
    ln_kernel<<<dim3(4096), blk, 0, stream>>>(x, ln1a, ln1b, xn1);
    gemm256_bt<0><<<dim3(192), dim3(512), 0, stream>>>(xn1, wqkvt, bqkv, qkv, 4096, 3072, 1024, 12);
    vtrans_kernel<<<dim3(64, 32, 2), blk, 0, stream>>>(qkv, vT);
    attn_kernel<<<dim3(32, 32), dim3(512), 0, stream>>>(qkv, vT, mask, ctx);
    gemm_bt<2, 0, 0><<<dim3(32, 8, 3), blk, 0, stream>>>(ctx, wot, nullptr, p0wo, x1, p1wo,
                                                         nullptr, 4096, 1024, 1024, 352);
    addbias2_ln_kernel<<<dim3(4096), blk, 0, stream>>>(x1, p0wo, p1wo, bo, x, ln2a, ln2b, xn2);

    // FFN1 (256^2 8-wave, relu) -> FFN2 (split-K=2) + reduce(+b2+x1)
    gemm256_bt<1><<<dim3(256), dim3(512), 0, stream>>>(xn2, w1t, b1, ff1, 4096, 4096, 1024, 16);
    gemm_bt<2, 0, 0><<<dim3(32, 8, 2), blk, 0, stream>>>(ff1, w2t, nullptr, p0f2, out, nullptr,
                                                         nullptr, 4096, 1024, 4096, 2048);
    addbias_kernel<<<dim3(4096), blk, 0, stream>>>(out, p0f2, b2, x1);
}

// Round 11
// 263.644 us; speedup vs baseline: 1.0611x; 1.0289x over previous
//
#include <hip/hip_runtime.h>
#include <hip/hip_bf16.h>

typedef __attribute__((ext_vector_type(8))) short short8;
typedef __attribute__((ext_vector_type(4))) float f32x4;
typedef __attribute__((ext_vector_type(4))) unsigned int u32x4;
using u16 = unsigned short;
typedef unsigned int u32;

__device__ __forceinline__ u16 f2bf(float f) {
    u32 u = __builtin_bit_cast(u32, f);
    u32 r = u + 0x7FFFu + ((u >> 16) & 1u);
    return (u16)(r >> 16);
}

__device__ __forceinline__ float bf2f(u32 w) {  // low 16 bits = bf16
    return __builtin_bit_cast(float, w << 16);
}
__device__ __forceinline__ float bf2f_hi(u32 w) {
    return __builtin_bit_cast(float, w & 0xFFFF0000u);
}

__device__ __forceinline__ float exp2fast(float x) {
    return __builtin_amdgcn_exp2f(x);  // v_exp_f32
}

__device__ __forceinline__ u32 cvtpk(float lo, float hi) {
    u32 r;
    asm("v_cvt_pk_bf16_f32 %0, %1, %2" : "=v"(r) : "v"(lo), "v"(hi));
    return r;
}

__device__ __forceinline__ void async_load16(const void* g, void* l) {
    __builtin_amdgcn_global_load_lds(
        (const __attribute__((address_space(1))) void*)g,
        (__attribute__((address_space(3))) void*)l, 16, 0, 0);
}

__device__ __forceinline__ void wg_barrier() {
    asm volatile("" ::: "memory");
    __builtin_amdgcn_s_barrier();
    asm volatile("" ::: "memory");
}

// ---------------- weight transpose + f32->bf16 convert: w[K][N] -> wt[N][K] ----------------
__global__ __launch_bounds__(256) void convt_kernel(const float* __restrict__ w,
                                                    u16* __restrict__ wt, int K, int N) {
    __shared__ float tile[32][33];
    int bn = blockIdx.x * 32, bk = blockIdx.y * 32;
    int tx = threadIdx.x & 31, ty = threadIdx.x >> 5;
#pragma unroll
    for (int i = 0; i < 4; i++)
        tile[ty + i * 8][tx] = w[(size_t)(bk + ty + i * 8) * N + bn + tx];
    __syncthreads();
#pragma unroll
    for (int i = 0; i < 4; i++)
        wt[(size_t)(bn + ty + i * 8) * K + bk + tx] = f2bf(tile[tx][ty + i * 8]);
}

// 4 square 1024x1024 transposes in one launch
__global__ __launch_bounds__(256) void convt4_kernel(const float* __restrict__ wa,
                                                     const float* __restrict__ wb,
                                                     const float* __restrict__ wc,
                                                     const float* __restrict__ wd,
                                                     u16* __restrict__ da,
                                                     u16* __restrict__ db,
                                                     u16* __restrict__ dc,
                                                     u16* __restrict__ dd) {
    __shared__ float tile[32][33];
    int z = blockIdx.z;
    const float* w = (z == 0) ? wa : (z == 1) ? wb : (z == 2) ? wc : wd;
    u16* wt = (z == 0) ? da : (z == 1) ? db : (z == 2) ? dc : dd;
    int bn = blockIdx.x * 32, bk = blockIdx.y * 32;
    int tx = threadIdx.x & 31, ty = threadIdx.x >> 5;
#pragma unroll
    for (int i = 0; i < 4; i++)
        tile[ty + i * 8][tx] = w[(size_t)(bk + ty + i * 8) * 1024 + bn + tx];
    __syncthreads();
#pragma unroll
    for (int i = 0; i < 4; i++)
        wt[(size_t)(bn + ty + i * 8) * 1024 + bk + tx] = f2bf(tile[tx][ty + i * 8]);
}

// ---------------- V transpose (bf16): qkv V-part [b][s][1024] -> vT[b*1024+col][2048] ----------------
__global__ __launch_bounds__(256) void vtrans_kernel(const u16* __restrict__ qkv,
                                                     u16* __restrict__ vT) {
    __shared__ u16 tile[32][33];
    int bs = blockIdx.x * 32;
    int bc = blockIdx.y * 32;
    int b  = blockIdx.z;
    int tx = threadIdx.x & 31, ty = threadIdx.x >> 5;
#pragma unroll
    for (int i = 0; i < 4; i++)
        tile[ty + i * 8][tx] = qkv[(size_t)(b * 2048 + bs + ty + i * 8) * 3072 + 2048 + bc + tx];
    __syncthreads();
#pragma unroll
    for (int i = 0; i < 4; i++)
        vT[(size_t)(b * 1024 + bc + ty + i * 8) * 2048 + bs + tx] = tile[tx][ty + i * 8];
}

// ---------------- LayerNorm (fp32 in, bf16 out) ----------------
__global__ __launch_bounds__(256) void ln_kernel(const float* __restrict__ x,
                                                 const float* __restrict__ ga,
                                                 const float* __restrict__ gb,
                                                 u16* __restrict__ out) {
    int row = blockIdx.x;
    const float4* xr = (const float4*)(x + (size_t)row * 1024);
    float4 v = xr[threadIdx.x];
    float s  = v.x + v.y + v.z + v.w;
    float s2 = v.x * v.x + v.y * v.y + v.z * v.z + v.w * v.w;
#pragma unroll
    for (int off = 32; off; off >>= 1) {
        s  += __shfl_down(s, off);
        s2 += __shfl_down(s2, off);
    }
    __shared__ float rs[4], rs2[4];
    int wid = threadIdx.x >> 6, lane = threadIdx.x & 63;
    if (lane == 0) { rs[wid] = s; rs2[wid] = s2; }
    __syncthreads();
    float S  = rs[0] + rs[1] + rs[2] + rs[3];
    float S2 = rs2[0] + rs2[1] + rs2[2] + rs2[3];
    float mean = S * (1.0f / 1024.0f);
    float var  = fmaxf((S2 - 1024.0f * mean * mean) * (1.0f / 1023.0f), 0.0f);
    float scale = ga[0] / (sqrtf(var) + 1e-6f);
    float shift = gb[0] - mean * scale;
    u16 h0 = f2bf(v.x * scale + shift);
    u16 h1 = f2bf(v.y * scale + shift);
    u16 h2 = f2bf(v.z * scale + shift);
    u16 h3 = f2bf(v.w * scale + shift);
    uint2 pv;
    pv.x = (u32)h0 | ((u32)h1 << 16);
    pv.y = (u32)h2 | ((u32)h3 << 16);
    *(uint2*)(out + (size_t)row * 1024 + threadIdx.x * 4) = pv;
}

// ---------------- bias concat ----------------
__global__ __launch_bounds__(256) void bias3_kernel(const float* __restrict__ a,
                                                    const float* __restrict__ b,
                                                    const float* __restrict__ c,
                                                    float* __restrict__ d) {
    int i = blockIdx.x * 256 + threadIdx.x;
    float v = (i < 1024) ? a[i] : ((i < 2048) ? b[i - 1024] : c[i - 2048]);
    d[i] = v;
}

// ---- fused reduce (3 bf16 partials): dst = dst + p0 + p1 + p2 + bias + resid ----
__global__ __launch_bounds__(256) void addbias3b_kernel(float* __restrict__ dst,
                                                        const u16* __restrict__ p0,
                                                        const u16* __restrict__ p1,
                                                        const u16* __restrict__ p2,
                                                        const float* __restrict__ bias,
                                                        const float* __restrict__ resid) {
    int i4 = blockIdx.x * 256 + threadIdx.x;
    float4 d  = ((const float4*)dst)[i4];
    uint2 ua = ((const uint2*)p0)[i4];
    uint2 ub = ((const uint2*)p1)[i4];
    uint2 uc = ((const uint2*)p2)[i4];
    float4 rr = ((const float4*)resid)[i4];
    float4 bb = *(const float4*)(bias + ((i4 * 4) & 1023));
    d.x += bf2f(ua.x) + bf2f(ub.x) + bf2f(uc.x) + bb.x + rr.x;
    d.y += bf2f_hi(ua.x) + bf2f_hi(ub.x) + bf2f_hi(uc.x) + bb.y + rr.y;
    d.z += bf2f(ua.y) + bf2f(ub.y) + bf2f(uc.y) + bb.z + rr.z;
    d.w += bf2f_hi(ua.y) + bf2f_hi(ub.y) + bf2f_hi(uc.y) + bb.w + rr.w;
    ((float4*)dst)[i4] = d;
}

// ---- fused reduce (2 partials) + LayerNorm: x1 = dst+p0+p1+bias+resid; xn = LN(x1) bf16 ----
__global__ __launch_bounds__(256) void addbias2_ln_kernel(float* __restrict__ dst,
                                                          const float* __restrict__ p0,
                                                          const float* __restrict__ p1,
                                                          const float* __restrict__ bias,
                                                          const float* __restrict__ resid,
                                                          const float* __restrict__ ga,
                                                          const float* __restrict__ gb,
                                                          u16* __restrict__ xn) {
    int row = blockIdx.x;
    int i4 = row * 256 + threadIdx.x;
    float4 d  = ((const float4*)dst)[i4];
    float4 pa = ((const float4*)p0)[i4];
    float4 pb = ((const float4*)p1)[i4];
    float4 rr = ((const float4*)resid)[i4];
    float4 bb = *(const float4*)(bias + threadIdx.x * 4);
    d.x += pa.x + pb.x + bb.x + rr.x;
    d.y += pa.y + pb.y + bb.y + rr.y;
    d.z += pa.z + pb.z + bb.z + rr.z;
    d.w += pa.w + pb.w + bb.w + rr.w;
    ((float4*)dst)[i4] = d;

    float s  = d.x + d.y + d.z + d.w;
    float s2 = d.x * d.x + d.y * d.y + d.z * d.z + d.w * d.w;
#pragma unroll
    for (int off = 32; off; off >>= 1) {
        s  += __shfl_down(s, off);
        s2 += __shfl_down(s2, off);
    }
    __shared__ float rs[4], rs2[4];
    int wid = threadIdx.x >> 6, lane = threadIdx.x & 63;
    if (lane == 0) { rs[wid] = s; rs2[wid] = s2; }
    __syncthreads();
    float S  = rs[0] + rs[1] + rs[2] + rs[3];
    float S2 = rs2[0] + rs2[1] + rs2[2] + rs2[3];
    float mean = S * (1.0f / 1024.0f);
    float var  = fmaxf((S2 - 1024.0f * mean * mean) * (1.0f / 1023.0f), 0.0f);
    float scale = ga[0] / (sqrtf(var) + 1e-6f);
    float shift = gb[0] - mean * scale;
    uint2 pv;
    pv.x = (u32)f2bf(d.x * scale + shift) | ((u32)f2bf(d.y * scale + shift) << 16);
    pv.y = (u32)f2bf(d.z * scale + shift) | ((u32)f2bf(d.w * scale + shift) << 16);
    *(uint2*)(xn + (size_t)row * 1024 + threadIdx.x * 4) = pv;
}

// ---------------- 256x256 8-wave GEMM, BK=64, 4-phase, swizzled LDS, counted vmcnt ----------------
// MODE 0: bf16 out + bias (+relu). MODE 2: split-K via blockIdx.y (kLen per split);
//   z < gridDim.y-1 -> bf16 partial to P[z]; z == gridDim.y-1 -> f32 partial to Cf.
template <int MODE, int RELU>
__global__ __launch_bounds__(512) void gemm256_bt(const u16* __restrict__ A,
                                                  const u16* __restrict__ Bt,
                                                  const float* __restrict__ bias,
                                                  u16* __restrict__ C,
                                                  u16* __restrict__ P0,
                                                  u16* __restrict__ P1,
                                                  u16* __restrict__ P2,
                                                  float* __restrict__ Cf,
                                                  int M, int N, int K, int tilesN, int kLen) {
    __shared__ u16 lds[2][2][16384];
    const int tid = threadIdx.x;
    const int lane = tid & 63, wid = tid >> 6;
    const int l15 = lane & 15, l4 = lane >> 4;
    const int wm = wid >> 2, wn = wid & 3;

    int nwg = gridDim.x;
    int bid = blockIdx.x;
    int swz = (bid & 7) * (nwg >> 3) + (bid >> 3);
    int ty = swz / tilesN, tx = swz % tilesN;
    const int kOff = blockIdx.y * kLen;

    const u16* Ag = A + (size_t)(ty * 256) * K;
    const u16* Bg = Bt + (size_t)(tx * 256) * K;

    auto stage_half = [&](int slot, int ab, int half, const u16* G, int k0) {
#pragma unroll
        for (int j = 0; j < 2; j++) {
            int off16 = half * 1024 + j * 512 + tid;
            int r = off16 >> 3;
            int gs = (off16 & 7) ^ (r & 7);
            const u16* src = G + (size_t)r * K + k0 + gs * 8;
            u16* dst = &lds[slot][ab][(size_t)(half * 1024 + j * 512 + (wid << 6)) * 8];
            async_load16(src, dst);
        }
    };

    f32x4 acc[8][4] = {};
    const int nT = kLen >> 6;

    stage_half(0, 0, 0, Ag, kOff);
    stage_half(0, 0, 1, Ag, kOff);
    stage_half(0, 1, 0, Bg, kOff);
    stage_half(0, 1, 1, Bg, kOff);
    __builtin_amdgcn_sched_barrier(0);

    for (int t = 0; t < nT; ++t) {
        const int cs = t & 1, ns = cs ^ 1;
        const int k1 = kOff + ((t + 1) << 6);
        const bool pf = (t + 1 < nT);
#pragma unroll
        for (int ph = 0; ph < 4; ++ph) {
            if (ph == 0 && pf) { stage_half(ns, 0, 0, Ag, k1); stage_half(ns, 0, 1, Ag, k1); }
            if (ph == 1 && pf) { stage_half(ns, 1, 0, Bg, k1); stage_half(ns, 1, 1, Bg, k1); }
            __builtin_amdgcn_sched_barrier(0);
            if (ph == 0) {
                if (pf) asm volatile("s_waitcnt vmcnt(4)" ::: "memory");
                else    asm volatile("s_waitcnt vmcnt(0)" ::: "memory");
            }
            wg_barrier();

            const int rh = ph >> 1, ch = ph & 1;
            const u16* la = &lds[cs][0][0];
            const u16* lb = &lds[cs][1][0];
            short8 af[4][2], bf[2][2];
#pragma unroll
            for (int m2 = 0; m2 < 4; m2++) {
                int ra = wm * 128 + rh * 64 + m2 * 16 + l15;
#pragma unroll
                for (int ks = 0; ks < 2; ks++) {
                    int sl = (l4 + ks * 4) ^ (ra & 7);
                    af[m2][ks] = *(const short8*)&la[ra * 64 + sl * 8];
                }
            }
#pragma unroll
            for (int n2 = 0; n2 < 2; n2++) {
                int rb = wn * 64 + ch * 32 + n2 * 16 + l15;
#pragma unroll
                for (int ks = 0; ks < 2; ks++) {
                    int sl = (l4 + ks * 4) ^ (rb & 7);
                    bf[n2][ks] = *(const short8*)&lb[rb * 64 + sl * 8];
                }
            }
            __builtin_amdgcn_s_setprio(1);
#pragma unroll
            for (int m2 = 0; m2 < 4; m2++)
#pragma unroll
                for (int n2 = 0; n2 < 2; n2++)
#pragma unroll
                    for (int ks = 0; ks < 2; ks++)
                        acc[rh * 4 + m2][ch * 2 + n2] = __builtin_amdgcn_mfma_f32_16x16x32_bf16(
                            af[m2][ks], bf[n2][ks], acc[rh * 4 + m2][ch * 2 + n2], 0, 0, 0);
            __builtin_amdgcn_s_setprio(0);
            wg_barrier();
        }
    }

    if (MODE == 0) {
#pragma unroll
        for (int mi = 0; mi < 8; mi++) {
            int row0 = ty * 256 + wm * 128 + (mi >> 2) * 64 + (mi & 3) * 16 + l4 * 4;
#pragma unroll
            for (int ni = 0; ni < 4; ni++) {
                int col = tx * 256 + wn * 64 + (ni >> 1) * 32 + (ni & 1) * 16 + l15;
                float bc = bias[col];
#pragma unroll
                for (int jj = 0; jj < 4; jj++) {
                    float v = acc[mi][ni][jj] + bc;
                    if (RELU) v = fmaxf(v, 0.0f);
                    C[(size_t)(row0 + jj) * N + col] = f2bf(v);
                }
            }
        }
    } else {
        int z = blockIdx.y;
        bool last = (z == gridDim.y - 1);
        u16* P = (z == 0) ? P0 : (z == 1) ? P1 : P2;
#pragma unroll
        for (int mi = 0; mi < 8; mi++) {
            int row0 = ty * 256 + wm * 128 + (mi >> 2) * 64 + (mi & 3) * 16 + l4 * 4;
#pragma unroll
            for (int ni = 0; ni < 4; ni++) {
                int col = tx * 256 + wn * 64 + (ni >> 1) * 32 + (ni & 1) * 16 + l15;
#pragma unroll
                for (int jj = 0; jj < 4; jj++) {
                    float v = acc[mi][ni][jj];
                    if (last) Cf[(size_t)(row0 + jj) * N + col] = v;
                    else      P[(size_t)(row0 + jj) * N + col] = f2bf(v);
                }
            }
        }
    }
}

// ---------------- bf16 GEMM, 2-phase double-buffered, split-K up to 3 (WO) ----------------
template <int MODE, int RELU, int RESID>
__global__ __launch_bounds__(256) void gemm_bt(const u16* __restrict__ A,
                                               const u16* __restrict__ Bt,
                                               const float* __restrict__ bias,
                                               void* __restrict__ C0,
                                               void* __restrict__ C1,
                                               void* __restrict__ Cp1,
                                               const float* __restrict__ resid,
                                               int M, int N, int K, int kLen) {
    __shared__ u16 As[8192];
    __shared__ u16 Bs[8192];
    int tid = threadIdx.x, lane = tid & 63, wid = tid >> 6;
    int l15 = lane & 15, l4 = lane >> 4;
    int rowA0 = blockIdx.x * 128;
    int rowB0 = blockIdx.y * 128;
    int kOff = blockIdx.z * kLen;
    int len = K - kOff; if (len > kLen) len = kLen;
    void* Cout = (blockIdx.z == gridDim.z - 1) ? C1 : (blockIdx.z == 0 ? C0 : Cp1);
    int waveM = wid >> 1, waveN = wid & 1;

    int fl = tid * 8;
    int r0 = fl >> 5, c0 = fl & 31;
    const u16* gA0 = A + (size_t)(rowA0 + r0) * K + c0 + kOff;
    const u16* gA1 = A + (size_t)(rowA0 + 64 + r0) * K + c0 + kOff;
    const u16* gB0 = Bt + (size_t)(rowB0 + r0) * K + c0 + kOff;
    const u16* gB1 = Bt + (size_t)(rowB0 + 64 + r0) * K + c0 + kOff;

    f32x4 acc[4][4] = {};
    const int nIter = len >> 5;

    async_load16(gA0, As + wid * 512);
    async_load16(gA1, As + 2048 + wid * 512);
    async_load16(gB0, Bs + wid * 512);
    async_load16(gB1, Bs + 2048 + wid * 512);

    int cur = 0, kb = 32;
    for (int it = 0; it < nIter; ++it) {
        asm volatile("s_waitcnt vmcnt(0)" ::: "memory");
        __builtin_amdgcn_s_barrier();
        if (it + 1 < nIter) {
            u16* a = As + (cur ^ 1) * 4096;
            u16* bb = Bs + (cur ^ 1) * 4096;
            async_load16(gA0 + kb, a + wid * 512);
            async_load16(gA1 + kb, a + 2048 + wid * 512);
            async_load16(gB0 + kb, bb + wid * 512);
            async_load16(gB1 + kb, bb + 2048 + wid * 512);
        }
        __builtin_amdgcn_sched_barrier(0);

        const u16* a = As + cur * 4096;
        const u16* bb = Bs + cur * 4096;
        short8 af[4], bf[4];
#pragma unroll
        for (int m = 0; m < 4; m++)
            af[m] = *(const short8*)&a[(waveM * 64 + m * 16 + l15) * 32 + l4 * 8];
#pragma unroll
        for (int n = 0; n < 4; n++)
            bf[n] = *(const short8*)&bb[(waveN * 64 + n * 16 + l15) * 32 + l4 * 8];
#pragma unroll
        for (int m = 0; m < 4; m++)
#pragma unroll
            for (int n = 0; n < 4; n++)
                acc[m][n] = __builtin_amdgcn_mfma_f32_16x16x32_bf16(af[m], bf[n], acc[m][n], 0, 0, 0);

        __builtin_amdgcn_s_barrier();
        cur ^= 1;
        kb += 32;
    }

#pragma unroll
    for (int m = 0; m < 4; m++) {
        int row = rowA0 + waveM * 64 + m * 16 + l4 * 4;
#pragma unroll
        for (int n = 0; n < 4; n++) {
            int col = rowB0 + waveN * 64 + n * 16 + l15;
            float bc = (MODE == 2) ? 0.0f : bias[col];
#pragma unroll
            for (int j = 0; j < 4; j++) {
                float v = acc[m][n][j] + bc;
                if (RELU) v = fmaxf(v, 0.0f);
                if (RESID) v += resid[(size_t)(row + j) * N + col];
                if (MODE == 1)
                    ((u16*)Cout)[(size_t)(row + j) * N + col] = f2bf(v);
                else
                    ((float*)Cout)[(size_t)(row + j) * N + col] = v;
            }
        }
    }
}

// ---------------- flash attention v6 (measured best): 8-wave split-S, PT-LDS P relayout ----------------
__global__ __launch_bounds__(512) void attn_kernel(const u16* __restrict__ qkv,
                                                   const u16* __restrict__ vT,
                                                   const int* __restrict__ mask,
                                                   u16* __restrict__ ctx) {
    const int S = 2048;
    const float C = 0.180336880f;  // 0.125 * log2(e)
    int qt = blockIdx.x;
    int bh = blockIdx.y;
    int b = bh >> 4, h = bh & 15;
    int tid = threadIdx.x;
    int wid = tid >> 6, lane = tid & 63;
    int l15 = lane & 15, l4 = lane >> 4;
    int g = wid >> 2, qw = wid & 3;

    __shared__ u16 Ks[2][64][72];
    __shared__ u16 Vs[2][64][72];
    __shared__ u32 PT[8][16][38];
    __shared__ float mbuf[2][4][16], lbuf[2][4][16];
    __shared__ int mflag;

    if (tid == 0) mflag = 1;
    __syncthreads();
    {
        const int* mrow = mask + b * S;
        int ok = 1;
#pragma unroll
        for (int i = 0; i < 4; i++) ok &= (mrow[tid * 4 + i] != 0);
        if (!ok) mflag = 0;
    }

    int qrow0 = qt * 64 + qw * 16;
    const u16* qb = qkv + (size_t)(b * S + qrow0) * 3072 + h * 64;
    short8 qf0 = *(const short8*)(qb + (size_t)l15 * 3072 + l4 * 8);
    short8 qf1 = *(const short8*)(qb + (size_t)l15 * 3072 + 32 + l4 * 8);

    f32x4 o[4] = {};
    float m_i = -1e30f, lp = 0.0f;
    __syncthreads();
    const int allones = mflag;
    const int* mrow = mask + b * S;

    int tl = tid & 255;
    int srow = tl >> 3, c8 = (tl & 7) * 8;
    const int kt0 = g * 16;
    short8 kreg[2], vreg[2];
#pragma unroll
    for (int p = 0; p < 2; p++) {
        int r = p * 32 + srow;
        kreg[p] = *(const short8*)(qkv + (size_t)(b * S + kt0 * 64 + r) * 3072 + 1024 + h * 64 + c8);
        vreg[p] = *(const short8*)(vT + (size_t)(bh * 64 + r) * 2048 + kt0 * 64 + c8);
    }

    for (int it = 0; it < 16; ++it) {
        const int kt = kt0 + it;
        wg_barrier();
#pragma unroll
        for (int p = 0; p < 2; p++) {
            int r = p * 32 + srow;
            *(short8*)&Ks[g][r][c8] = kreg[p];
            *(short8*)&Vs[g][r][c8] = vreg[p];
        }
        if (it + 1 < 16) {
#pragma unroll
            for (int p = 0; p < 2; p++) {
                int r = p * 32 + srow;
                kreg[p] = *(const short8*)(qkv + (size_t)(b * S + (kt + 1) * 64 + r) * 3072 + 1024 + h * 64 + c8);
                vreg[p] = *(const short8*)(vT + (size_t)(bh * 64 + r) * 2048 + (kt + 1) * 64 + c8);
            }
        }
        asm volatile("s_waitcnt lgkmcnt(0)" ::: "memory");
        wg_barrier();

        float sc[4][4];
#pragma unroll
        for (int kc = 0; kc < 4; kc++) {
            short8 kf0 = *(const short8*)&Ks[g][kc * 16 + l15][l4 * 8];
            short8 kf1 = *(const short8*)&Ks[g][kc * 16 + l15][32 + l4 * 8];
            f32x4 a = {};
            a = __builtin_amdgcn_mfma_f32_16x16x32_bf16(kf0, qf0, a, 0, 0, 0);
            a = __builtin_amdgcn_mfma_f32_16x16x32_bf16(kf1, qf1, a, 0, 0, 0);
            if (allones) {
#pragma unroll
                for (int j = 0; j < 4; j++) sc[kc][j] = a[j];
            } else {
#pragma unroll
                for (int j = 0; j < 4; j++) {
                    int mk = mrow[kt * 64 + kc * 16 + l4 * 4 + j];
                    sc[kc][j] = mk ? a[j] : -1e9f;
                }
            }
        }

        float lm = sc[0][0];
#pragma unroll
        for (int kc = 0; kc < 4; kc++)
#pragma unroll
            for (int j = 0; j < 4; j++) lm = fmaxf(lm, sc[kc][j]);
        if (!__all(lm <= m_i + 64.0f)) {
            float t = lm;
            t = fmaxf(t, __shfl_xor(t, 16));
            t = fmaxf(t, __shfl_xor(t, 32));
            float newm = fmaxf(m_i, t);
            float r = exp2fast((m_i - newm) * C);
            lp *= r;
            float rr0 = __shfl(r, l4 * 4 + 0);
            float rr1 = __shfl(r, l4 * 4 + 1);
            float rr2 = __shfl(r, l4 * 4 + 2);
            float rr3 = __shfl(r, l4 * 4 + 3);
#pragma unroll
            for (int dc = 0; dc < 4; dc++) {
                o[dc][0] *= rr0; o[dc][1] *= rr1; o[dc][2] *= rr2; o[dc][3] *= rr3;
            }
            m_i = newm;
        }

        float nb = -m_i * C;
#pragma unroll
        for (int kc = 0; kc < 4; kc++) {
            float p0 = exp2fast(fmaf(sc[kc][0], C, nb));
            float p1 = exp2fast(fmaf(sc[kc][1], C, nb));
            float p2 = exp2fast(fmaf(sc[kc][2], C, nb));
            float p3 = exp2fast(fmaf(sc[kc][3], C, nb));
            lp += (p0 + p1) + (p2 + p3);
            uint2 w;
            w.x = cvtpk(p0, p1);
            w.y = cvtpk(p2, p3);
            *(uint2*)&PT[wid][l15][kc * 8 + l4 * 2] = w;
        }

        uint2 r01 = *(const uint2*)&PT[wid][l15][l4 * 4];
        uint2 r23 = *(const uint2*)&PT[wid][l15][l4 * 4 + 2];
        uint2 r45 = *(const uint2*)&PT[wid][l15][16 + l4 * 4];
        uint2 r67 = *(const uint2*)&PT[wid][l15][16 + l4 * 4 + 2];
        u32x4 w0 = {r01.x, r01.y, r23.x, r23.y};
        u32x4 w1 = {r45.x, r45.y, r67.x, r67.y};
        short8 pa0 = __builtin_bit_cast(short8, w0);
        short8 pa1 = __builtin_bit_cast(short8, w1);

#pragma unroll
        for (int dc = 0; dc < 4; dc++) {
            short8 vf0 = *(const short8*)&Vs[g][dc * 16 + l15][l4 * 8];
            short8 vf1 = *(const short8*)&Vs[g][dc * 16 + l15][32 + l4 * 8];
            o[dc] = __builtin_amdgcn_mfma_f32_16x16x32_bf16(pa0, vf0, o[dc], 0, 0, 0);
            o[dc] = __builtin_amdgcn_mfma_f32_16x16x32_bf16(pa1, vf1, o[dc], 0, 0, 0);
        }
    }

    // -------- combine the two groups --------
    float lt = lp;
    lt += __shfl_xor(lt, 16);
    lt += __shfl_xor(lt, 32);
    if (l4 == 0) { mbuf[g][qw][l15] = m_i; lbuf[g][qw][l15] = lt; }
    __syncthreads();
    float mo = mbuf[g ^ 1][qw][l15], lo = lbuf[g ^ 1][qw][l15];
    float M  = fmaxf(m_i, mo);
    float rs = exp2fast((m_i - M) * C);
    float ro = exp2fast((mo - M) * C);
    float inv = 1.0f / (rs * lt + ro * lo);
    float rs_j[4], iv_j[4];
#pragma unroll
    for (int j = 0; j < 4; j++) {
        rs_j[j] = __shfl(rs,  l4 * 4 + j);
        iv_j[j] = __shfl(inv, l4 * 4 + j);
    }

    float* obuf = (float*)&Ks[0][0][0];  // 16 KB overlay on dead Ks
#pragma unroll
    for (int c = 0; c < 2; c++) {
        int dce = (g ^ 1) * 2 + c;
#pragma unroll
        for (int j = 0; j < 4; j++)
            obuf[(((g * 4 + qw) * 16) + l4 * 4 + j) * 32 + c * 16 + l15] = o[dce][j] * rs_j[j];
    }
    __syncthreads();
#pragma unroll
    for (int c = 0; c < 2; c++) {
        int dco = g * 2 + c;
#pragma unroll
        for (int j = 0; j < 4; j++) {
            float peer = obuf[((((g ^ 1) * 4 + qw) * 16) + l4 * 4 + j) * 32 + c * 16 + l15];
            float val = (o[dco][j] * rs_j[j] + peer) * iv_j[j];
            int row = qrow0 + l4 * 4 + j;
            ctx[(size_t)(b * S + row) * 1024 + h * 64 + dco * 16 + l15] = f2bf(val);
        }
    }
}

// ---------------- launcher ----------------
extern "C" void kernel_launch(void* const* d_in, const int* in_sizes, int n_in,
                              void* d_out, int out_size, void* d_ws, size_t ws_size,
                              hipStream_t stream) {
    const float* x    = (const float*)d_in[0];
    const int*   mask = (const int*)d_in[1];
    const float* wq   = (const float*)d_in[2];
    const float* bq   = (const float*)d_in[3];
    const float* wk   = (const float*)d_in[4];
    const float* bk   = (const float*)d_in[5];
    const float* wv   = (const float*)d_in[6];
    const float* bv   = (const float*)d_in[7];
    const float* wo   = (const float*)d_in[8];
    const float* bo   = (const float*)d_in[9];
    const float* w1   = (const float*)d_in[10];
    const float* b1   = (const float*)d_in[11];
    const float* w2   = (const float*)d_in[12];
    const float* b2   = (const float*)d_in[13];
    const float* ln1a = (const float*)d_in[14];
    const float* ln1b = (const float*)d_in[15];
    const float* ln2a = (const float*)d_in[16];
    const float* ln2b = (const float*)d_in[17];
    float* out = (float*)d_out;

    char* ws = (char*)d_ws;
    u16*   wqkvt = (u16*)(ws + 0);            //  6 MB (dead after QKV)
    u16*   wot   = (u16*)(ws + 6291456);      //  2 MB (dead after WO)
    u16*   w1t   = (u16*)(ws + 8388608);      //  8 MB (dead after FFN1)
    u16*   w2t   = (u16*)(ws + 16777216);     //  8 MB (live through FFN2)
    float* bqkv  = (float*)(ws + 25165824);   // 12 KB
    char*  regA  = ws + 26214400;
    u16*   xn1   = (u16*)(regA + 0);          //  8 MB
    u16*   vT    = (u16*)(regA + 0);          //  8 MB (aliases xn1)
    u16*   qkv   = (u16*)(regA + 8388608);    // 24 MB
    u16*   ctx   = (u16*)(regA + 33554432);   //  8 MB
    float* p0wo  = (float*)(regA + 0);        // 16 MB (vT+qkv dead by WO time)
    float* p1wo  = (float*)(regA + 16777216); // 16 MB
    float* x1    = (float*)(ws + 68157440);   // 16 MB
    u16*   xn2   = (u16*)(regA + 0);          //  8 MB (WO partials dead after reduce)
    u16*   ff1   = (u16*)(regA + 8388608);    // 32 MB
    // FFN2 bf16 partials (dead regions by FFN2 time):
    u16*   pb0   = (u16*)(ws + 0);            //  8 MB (over wqkvt)
    u16*   pb1   = (u16*)(ws + 8388608);      //  8 MB (over w1t)
    u16*   pb2   = (u16*)(regA + 0);          //  8 MB (over xn2, dead after FFN1)

    dim3 blk(256);

    convt4_kernel<<<dim3(32, 32, 4), blk, 0, stream>>>(
        wq, wk, wv, wo, wqkvt, wqkvt + 1024 * 1024, wqkvt + 2048 * 1024, wot);
    convt_kernel<<<dim3(128, 32), blk, 0, stream>>>(w1, w1t, 1024, 4096);
    convt_kernel<<<dim3(32, 128), blk, 0, stream>>>(w2, w2t, 4096, 1024);
    bias3_kernel<<<dim3(12), blk, 0, stream>>>(bq, bk, bv, bqkv);

    // LN1 -> QKV (256^2 8-wave) -> attn -> WO (split-K=3) + fused reduce+bo+x+LN2
    ln_kernel<<<dim3(4096), blk, 0, stream>>>(x, ln1a, ln1b, xn1);
    gemm256_bt<0, 0><<<dim3(192, 1), dim3(512), 0, stream>>>(
        xn1, wqkvt, bqkv, qkv, nullptr, nullptr, nullptr, nullptr, 4096, 3072, 1024, 12, 1024);
    vtrans_kernel<<<dim3(64, 32, 2), blk, 0, stream>>>(qkv, vT);
    attn_kernel<<<dim3(32, 32), dim3(512), 0, stream>>>(qkv, vT, mask, ctx);
    gemm_bt<2, 0, 0><<<dim3(32, 8, 3), blk, 0, stream>>>(ctx, wot, nullptr, p0wo, x1, p1wo,
                                                         nullptr, 4096, 1024, 1024, 352);
    addbias2_ln_kernel<<<dim3(4096), blk, 0, stream>>>(x1, p0wo, p1wo, bo, x, ln2a, ln2b, xn2);

    // FFN1 (256^2 8-wave, relu) -> FFN2 (256^2 8-wave, split-K=4) + reduce(+b2+x1)
    gemm256_bt<0, 1><<<dim3(256, 1), dim3(512), 0, stream>>>(
        xn2, w1t, b1, ff1, nullptr, nullptr, nullptr, nullptr, 4096, 4096, 1024, 16, 1024);
    gemm256_bt<2, 0><<<dim3(64, 4), dim3(512), 0, stream>>>(
        ff1, w2t, nullptr, nullptr, pb0, pb1, pb2, out, 4096, 1024, 4096, 4, 1024);
    addbias3b_kernel<<<dim3(4096), blk, 0, stream>>>(out, pb0, pb1, pb2, b2, x1);
}